// Round 2
// baseline (4170.484 us; speedup 1.0000x reference)
//
#include <hip/hip_runtime.h>

// Kalman filter fused step, fp32.
// D=1024, M=512, C=256, B=8192.
// Inputs: state[D,B], state_cov[D,D], meas[M,B], control[C,B],
//         F[D,D], Q[D,D], Bc[D,C], H[M,D], R[M,M]   (all row-major fp32)
// Outputs (concat): state_n[D,B], cov_n[D,D]
// Scratch layout is aliased aggressively: peak d_ws use ~14.8 MB.

static constexpr int Dd = 1024;
static constexpr int Mm = 512;
static constexpr int Cc = 256;
static constexpr int Bb = 8192;
static constexpr int BCHUNK = 2048;  // B-dim chunk for innovation panels

// ---------------------------------------------------------------------------
// Generic tiled fp32 GEMM:  C = ADD + sign * (A @ opB)
//   A:[M,K] lda ; opB = B[K,N] (ldb) if !TRANSB, else B^T with B:[N,K] (ldb)
//   ADD: optional [M,N] ldadd (nullptr -> 0). C:[M,N] ldc.
// Tile 128x128, BK=16, 256 threads, 8x8 per thread.
// Requires K % 16 == 0 and float4-aligned rows (lda/ldb/ldc/ldadd % 4 == 0).
// ---------------------------------------------------------------------------
template <bool TRANSB>
__global__ __launch_bounds__(256) void gemm_f32(
    float* __restrict__ Cp, int ldc,
    const float* __restrict__ Ap, int lda,
    const float* __restrict__ Bp, int ldb,
    const float* __restrict__ ADDp, int ldadd,
    int M, int N, int K, float sign)
{
    __shared__ float As[16][132];  // As[k][m], +4 pad (132*4=528 is 16B-mult)
    __shared__ float Bs[16][132];  // Bs[k][n]

    const int tid  = threadIdx.x;
    const int row0 = blockIdx.y * 128;
    const int col0 = blockIdx.x * 128;
    const int tr   = tid >> 4;   // 0..15
    const int tc   = tid & 15;   // 0..15

    float acc[8][8];
#pragma unroll
    for (int i = 0; i < 8; ++i)
#pragma unroll
        for (int j = 0; j < 8; ++j) acc[i][j] = 0.f;

    for (int k0 = 0; k0 < K; k0 += 16) {
        // ---- load A tile (128 rows x 16 k), store transposed As[k][m] ----
#pragma unroll
        for (int l = 0; l < 2; ++l) {
            const int f    = tid + l * 256;   // 0..511 float4s
            const int r    = f >> 2;          // 0..127
            const int kq   = (f & 3) << 2;    // 0,4,8,12
            const int grow = row0 + r;
            float4 v = make_float4(0.f, 0.f, 0.f, 0.f);
            if (grow < M)
                v = *reinterpret_cast<const float4*>(Ap + (size_t)grow * lda + k0 + kq);
            As[kq + 0][r] = v.x;
            As[kq + 1][r] = v.y;
            As[kq + 2][r] = v.z;
            As[kq + 3][r] = v.w;
        }
        // ---- load B tile -> Bs[k][n] ----
        if (!TRANSB) {
#pragma unroll
            for (int l = 0; l < 2; ++l) {
                const int f    = tid + l * 256;
                const int kk   = f >> 5;         // 0..15
                const int cq   = (f & 31) << 2;  // 0..124
                const int gcol = col0 + cq;
                float4 v = make_float4(0.f, 0.f, 0.f, 0.f);
                if (gcol + 3 < N)
                    v = *reinterpret_cast<const float4*>(Bp + (size_t)(k0 + kk) * ldb + gcol);
                *reinterpret_cast<float4*>(&Bs[kk][cq]) = v;
            }
        } else {
#pragma unroll
            for (int l = 0; l < 2; ++l) {
                const int f    = tid + l * 256;
                const int n    = f >> 2;        // 0..127
                const int kq   = (f & 3) << 2;  // 0,4,8,12
                const int gcol = col0 + n;
                float4 v = make_float4(0.f, 0.f, 0.f, 0.f);
                if (gcol < N)
                    v = *reinterpret_cast<const float4*>(Bp + (size_t)gcol * ldb + k0 + kq);
                Bs[kq + 0][n] = v.x;
                Bs[kq + 1][n] = v.y;
                Bs[kq + 2][n] = v.z;
                Bs[kq + 3][n] = v.w;
            }
        }
        __syncthreads();

#pragma unroll
        for (int kk = 0; kk < 16; ++kk) {
            const float4 a0 = *reinterpret_cast<const float4*>(&As[kk][tr * 8]);
            const float4 a1 = *reinterpret_cast<const float4*>(&As[kk][tr * 8 + 4]);
            const float4 b0 = *reinterpret_cast<const float4*>(&Bs[kk][tc * 8]);
            const float4 b1 = *reinterpret_cast<const float4*>(&Bs[kk][tc * 8 + 4]);
            const float a_frag[8] = {a0.x, a0.y, a0.z, a0.w, a1.x, a1.y, a1.z, a1.w};
            const float b_frag[8] = {b0.x, b0.y, b0.z, b0.w, b1.x, b1.y, b1.z, b1.w};
#pragma unroll
            for (int i = 0; i < 8; ++i)
#pragma unroll
                for (int j = 0; j < 8; ++j)
                    acc[i][j] = fmaf(a_frag[i], b_frag[j], acc[i][j]);
        }
        __syncthreads();
    }

    // ---- epilogue ----
#pragma unroll
    for (int i = 0; i < 8; ++i) {
        const int grow = row0 + tr * 8 + i;
        if (grow >= M) continue;
        const int gcol = col0 + tc * 8;
        if (gcol + 7 < N) {
            float4 o0, o1;
            if (ADDp) {
                const float4 d0 = *reinterpret_cast<const float4*>(ADDp + (size_t)grow * ldadd + gcol);
                const float4 d1 = *reinterpret_cast<const float4*>(ADDp + (size_t)grow * ldadd + gcol + 4);
                o0.x = fmaf(sign, acc[i][0], d0.x);
                o0.y = fmaf(sign, acc[i][1], d0.y);
                o0.z = fmaf(sign, acc[i][2], d0.z);
                o0.w = fmaf(sign, acc[i][3], d0.w);
                o1.x = fmaf(sign, acc[i][4], d1.x);
                o1.y = fmaf(sign, acc[i][5], d1.y);
                o1.z = fmaf(sign, acc[i][6], d1.z);
                o1.w = fmaf(sign, acc[i][7], d1.w);
            } else {
                o0.x = sign * acc[i][0];
                o0.y = sign * acc[i][1];
                o0.z = sign * acc[i][2];
                o0.w = sign * acc[i][3];
                o1.x = sign * acc[i][4];
                o1.y = sign * acc[i][5];
                o1.z = sign * acc[i][6];
                o1.w = sign * acc[i][7];
            }
            *reinterpret_cast<float4*>(Cp + (size_t)grow * ldc + gcol)     = o0;
            *reinterpret_cast<float4*>(Cp + (size_t)grow * ldc + gcol + 4) = o1;
        } else {
#pragma unroll
            for (int j = 0; j < 8; ++j) {
                const int gc = gcol + j;
                if (gc < N) {
                    const float add = ADDp ? ADDp[(size_t)grow * ldadd + gc] : 0.f;
                    Cp[(size_t)grow * ldc + gc] = fmaf(sign, acc[i][j], add);
                }
            }
        }
    }
}

// ---------------------------------------------------------------------------
// 64x64 block inverse via Gauss-Jordan in LDS (no pivoting; S is PSD + ~I,
// well conditioned). One workgroup of 256.
// Reads W[kb*64.., kb*64..] (ldw), writes Dinv[64*64].
// ---------------------------------------------------------------------------
__global__ __launch_bounds__(256) void inv64_kernel(
    const float* __restrict__ W, int ldw, int kb, float* __restrict__ Dinv)
{
    __shared__ float T[64][129];  // augmented [A | I]
    __shared__ float multcol[64];
    const int tid = threadIdx.x;

    for (int idx = tid; idx < 64 * 64; idx += 256) {
        const int r = idx >> 6, c = idx & 63;
        T[r][c]      = W[(size_t)(kb * 64 + r) * ldw + kb * 64 + c];
        T[r][64 + c] = (r == c) ? 1.f : 0.f;
    }
    __syncthreads();

    for (int p = 0; p < 64; ++p) {
        const float rp = 1.f / T[p][p];
        __syncthreads();
        if (tid < 128) T[p][tid] *= rp;                          // scale pivot row
        if (tid >= 128 && tid < 192) multcol[tid - 128] = T[tid - 128][p];
        __syncthreads();
        for (int idx = tid; idx < 64 * 128; idx += 256) {
            const int r = idx >> 7, c = idx & 127;
            if (r != p) T[r][c] = fmaf(-multcol[r], T[p][c], T[r][c]);
        }
        __syncthreads();
    }

    for (int idx = tid; idx < 64 * 64; idx += 256) {
        const int r = idx >> 6, c = idx & 63;
        Dinv[idx] = T[r][64 + c];
    }
}

// Right half of augmented W gets the identity.
__global__ void init_eye_kernel(float* __restrict__ W)
{
    const int idx = blockIdx.x * 256 + threadIdx.x;  // 512*512
    if (idx < 512 * 512) {
        const int r = idx >> 9, c = idx & 511;
        W[(size_t)r * 1024 + 512 + c] = (r == c) ? 1.f : 0.f;
    }
}

// Snapshot multiplier columns; zero the pivot-block rows so the elimination
// GEMM can update all 512 rows uniformly (pivot rows get exact -0*x = no-op).
__global__ void multcopy_kernel(const float* __restrict__ W, float* __restrict__ Mbuf, int kb)
{
    const int idx = blockIdx.x * 256 + threadIdx.x;  // 512*64
    if (idx < 512 * 64) {
        const int r = idx >> 6, c = idx & 63;
        const float v = W[(size_t)r * 1024 + kb * 64 + c];
        Mbuf[idx] = ((r >> 6) == kb) ? 0.f : v;
    }
}

extern "C" void kernel_launch(void* const* d_in, const int* in_sizes, int n_in,
                              void* d_out, int out_size, void* d_ws, size_t ws_size,
                              hipStream_t stream)
{
    const float* state   = (const float*)d_in[0];  // [D,B]
    const float* cov     = (const float*)d_in[1];  // [D,D]
    const float* meas    = (const float*)d_in[2];  // [M,B]
    const float* control = (const float*)d_in[3];  // [C,B]
    const float* F       = (const float*)d_in[4];  // [D,D]
    const float* Q       = (const float*)d_in[5];  // [D,D]
    const float* Bc      = (const float*)d_in[6];  // [D,C]
    const float* H       = (const float*)d_in[7];  // [M,D]
    const float* R       = (const float*)d_in[8];  // [M,M]

    float* out_state = (float*)d_out;                   // state_n [D,B] (also holds state_p)
    float* out_cov   = out_state + (size_t)Dd * Bb;     // cov_n [D,D]
    float* T1        = out_cov;                         // borrow cov_n slot for F@state_cov

    // scratch (aliased; peak ~14.8 MB)
    float* ws    = (float*)d_ws;
    float* cov_p = ws;  ws += (size_t)Dd * Dd;    // [D,D]           4 MB
    float* HCP   = ws;  ws += (size_t)Mm * Dd;    // HC then PHT     2 MB
    float* W     = ws;  ws += (size_t)Mm * 1024;  // augmented [S|I] 2 MB
    float* Mbuf  = ws;  ws += (size_t)Mm * 64;    // multiplier panel
    float* Dinv  = ws;  ws += 64 * 64;            // diag-block inverse
    float* Kg    = ws;  ws += (size_t)Dd * Mm;    // Kalman gain     2 MB
    float* KHI   = ws;  ws += (size_t)Dd * Dd;    // KH then innov-chunks 4 MB

    const dim3 blk(256);

    // ---------------- covariance chain ----------------
    // T1 = F @ state_cov            (T1 lives in out_cov slot)
    gemm_f32<false><<<dim3(Dd / 128, Dd / 128), blk, 0, stream>>>(
        T1, Dd, F, Dd, cov, Dd, nullptr, 0, Dd, Dd, Dd, 1.f);
    // cov_p = T1 @ F^T + Q
    gemm_f32<true><<<dim3(Dd / 128, Dd / 128), blk, 0, stream>>>(
        cov_p, Dd, T1, Dd, F, Dd, Q, Dd, Dd, Dd, Dd, 1.f);
    // HC = H @ cov_p
    gemm_f32<false><<<dim3(Dd / 128, Mm / 128), blk, 0, stream>>>(
        HCP, Dd, H, Dd, cov_p, Dd, nullptr, 0, Mm, Dd, Dd, 1.f);
    // S = HC @ H^T + R -> left half of W (ldc = 1024)
    gemm_f32<true><<<dim3(Mm / 128, Mm / 128), blk, 0, stream>>>(
        W, 1024, HCP, Dd, H, Dd, R, Mm, Mm, Mm, Dd, 1.f);
    // right half of W = I
    init_eye_kernel<<<dim3((512 * 512) / 256), blk, 0, stream>>>(W);

    // blocked Gauss-Jordan: W = [S | I] -> [I | S^-1]
    for (int kb = 0; kb < 8; ++kb) {
        inv64_kernel<<<dim3(1), blk, 0, stream>>>(W, 1024, kb, Dinv);
        // scale pivot rows: W[kb,:] = Dinv @ W[kb,:]   (in place, col-tile safe)
        gemm_f32<false><<<dim3(1024 / 128, 1), blk, 0, stream>>>(
            W + (size_t)kb * 64 * 1024, 1024, Dinv, 64,
            W + (size_t)kb * 64 * 1024, 1024, nullptr, 0, 64, 1024, 64, 1.f);
        multcopy_kernel<<<dim3((512 * 64) / 256), blk, 0, stream>>>(W, Mbuf, kb);
        // eliminate: W -= Mbuf @ Wpivot  (pivot rows have zero multipliers)
        gemm_f32<false><<<dim3(1024 / 128, 512 / 128), blk, 0, stream>>>(
            W, 1024, Mbuf, 64, W + (size_t)kb * 64 * 1024, 1024,
            W, 1024, 512, 1024, 64, -1.f);
    }
    float* Sinv = W + 512;  // right half, ld 1024

    // PHT = cov_p @ H^T   (reuses HC slot; HC dead after S)
    gemm_f32<true><<<dim3(Mm / 128, Dd / 128), blk, 0, stream>>>(
        HCP, Mm, cov_p, Dd, H, Dd, nullptr, 0, Dd, Mm, Dd, 1.f);
    // Kg = PHT @ Sinv
    gemm_f32<false><<<dim3(Mm / 128, Dd / 128), blk, 0, stream>>>(
        Kg, Mm, HCP, Mm, Sinv, 1024, nullptr, 0, Dd, Mm, Mm, 1.f);
    // KH = Kg @ H          (KHI slot)
    gemm_f32<false><<<dim3(Dd / 128, Dd / 128), blk, 0, stream>>>(
        KHI, Dd, Kg, Mm, H, Dd, nullptr, 0, Dd, Dd, Mm, 1.f);
    // cov_n = cov_p - KH @ cov_p     (out_cov; T1 long dead)
    gemm_f32<false><<<dim3(Dd / 128, Dd / 128), blk, 0, stream>>>(
        out_cov, Dd, KHI, Dd, cov_p, Dd, cov_p, Dd, Dd, Dd, Dd, -1.f);

    // ---------------- state chain ----------------
    // state_p = F @ state -> out_state
    gemm_f32<false><<<dim3(Bb / 128, Dd / 128), blk, 0, stream>>>(
        out_state, Bb, F, Dd, state, Bb, nullptr, 0, Dd, Bb, Dd, 1.f);
    // state_p += Bc @ control (in place)
    gemm_f32<false><<<dim3(Bb / 128, Dd / 128), blk, 0, stream>>>(
        out_state, Bb, Bc, Cc, control, Bb, out_state, Bb, Dd, Bb, Cc, 1.f);

    // innovation + gain update, chunked over B (KHI slot reused as [M,BCHUNK])
    for (int b0 = 0; b0 < Bb; b0 += BCHUNK) {
        float* innov_c = KHI;  // [512, BCHUNK], 4 MB
        // innov_c = meas[:,b0:] - H @ state_p[:,b0:]
        gemm_f32<false><<<dim3(BCHUNK / 128, Mm / 128), blk, 0, stream>>>(
            innov_c, BCHUNK, H, Dd, out_state + b0, Bb, meas + b0, Bb,
            Mm, BCHUNK, Dd, -1.f);
        // state_n[:,b0:] = state_p[:,b0:] + Kg @ innov_c   (in place)
        gemm_f32<false><<<dim3(BCHUNK / 128, Dd / 128), blk, 0, stream>>>(
            out_state + b0, Bb, Kg, Mm, innov_c, BCHUNK, out_state + b0, Bb,
            Dd, BCHUNK, Mm, 1.f);
    }
}

// Round 3
// 3162.403 us; speedup vs baseline: 1.3188x; 1.3188x over previous
//
#include <hip/hip_runtime.h>

// Kalman filter fused step. D=1024, M=512, C=256, B=8192, fp32 in/out.
// Fast path: split-bf16 (hi+lo) MFMA GEMMs (3 mfma per product, fp32 acc).
// Fallback (ws_size too small): round-2 fp32 vector-ALU path.

static constexpr int Dd = 1024;
static constexpr int Mm = 512;
static constexpr int Cc = 256;
static constexpr int Bb = 8192;

typedef __bf16 bf16x8 __attribute__((ext_vector_type(8)));
typedef float f32x4 __attribute__((ext_vector_type(4)));

// ===========================================================================
// fp32 tiled GEMM (fallback path + GJ eliminate): C = ADD + sign*(A@opB)
// ===========================================================================
template <bool TRANSB>
__global__ __launch_bounds__(256) void gemm_f32(
    float* __restrict__ Cp, int ldc,
    const float* __restrict__ Ap, int lda,
    const float* __restrict__ Bp, int ldb,
    const float* __restrict__ ADDp, int ldadd,
    int M, int N, int K, float sign)
{
    __shared__ float As[16][132];
    __shared__ float Bs[16][132];

    const int tid  = threadIdx.x;
    const int row0 = blockIdx.y * 128;
    const int col0 = blockIdx.x * 128;
    const int tr   = tid >> 4;
    const int tc   = tid & 15;

    float acc[8][8];
#pragma unroll
    for (int i = 0; i < 8; ++i)
#pragma unroll
        for (int j = 0; j < 8; ++j) acc[i][j] = 0.f;

    for (int k0 = 0; k0 < K; k0 += 16) {
#pragma unroll
        for (int l = 0; l < 2; ++l) {
            const int f    = tid + l * 256;
            const int r    = f >> 2;
            const int kq   = (f & 3) << 2;
            const int grow = row0 + r;
            float4 v = make_float4(0.f, 0.f, 0.f, 0.f);
            if (grow < M)
                v = *reinterpret_cast<const float4*>(Ap + (size_t)grow * lda + k0 + kq);
            As[kq + 0][r] = v.x;
            As[kq + 1][r] = v.y;
            As[kq + 2][r] = v.z;
            As[kq + 3][r] = v.w;
        }
        if (!TRANSB) {
#pragma unroll
            for (int l = 0; l < 2; ++l) {
                const int f    = tid + l * 256;
                const int kk   = f >> 5;
                const int cq   = (f & 31) << 2;
                const int gcol = col0 + cq;
                float4 v = make_float4(0.f, 0.f, 0.f, 0.f);
                if (gcol + 3 < N)
                    v = *reinterpret_cast<const float4*>(Bp + (size_t)(k0 + kk) * ldb + gcol);
                *reinterpret_cast<float4*>(&Bs[kk][cq]) = v;
            }
        } else {
#pragma unroll
            for (int l = 0; l < 2; ++l) {
                const int f    = tid + l * 256;
                const int n    = f >> 2;
                const int kq   = (f & 3) << 2;
                const int gcol = col0 + n;
                float4 v = make_float4(0.f, 0.f, 0.f, 0.f);
                if (gcol < N)
                    v = *reinterpret_cast<const float4*>(Bp + (size_t)gcol * ldb + k0 + kq);
                Bs[kq + 0][n] = v.x;
                Bs[kq + 1][n] = v.y;
                Bs[kq + 2][n] = v.z;
                Bs[kq + 3][n] = v.w;
            }
        }
        __syncthreads();

#pragma unroll
        for (int kk = 0; kk < 16; ++kk) {
            const float4 a0 = *reinterpret_cast<const float4*>(&As[kk][tr * 8]);
            const float4 a1 = *reinterpret_cast<const float4*>(&As[kk][tr * 8 + 4]);
            const float4 b0 = *reinterpret_cast<const float4*>(&Bs[kk][tc * 8]);
            const float4 b1 = *reinterpret_cast<const float4*>(&Bs[kk][tc * 8 + 4]);
            const float a_frag[8] = {a0.x, a0.y, a0.z, a0.w, a1.x, a1.y, a1.z, a1.w};
            const float b_frag[8] = {b0.x, b0.y, b0.z, b0.w, b1.x, b1.y, b1.z, b1.w};
#pragma unroll
            for (int i = 0; i < 8; ++i)
#pragma unroll
                for (int j = 0; j < 8; ++j)
                    acc[i][j] = fmaf(a_frag[i], b_frag[j], acc[i][j]);
        }
        __syncthreads();
    }

#pragma unroll
    for (int i = 0; i < 8; ++i) {
        const int grow = row0 + tr * 8 + i;
        if (grow >= M) continue;
        const int gcol = col0 + tc * 8;
        if (gcol + 7 < N) {
            float4 o0, o1;
            if (ADDp) {
                const float4 d0 = *reinterpret_cast<const float4*>(ADDp + (size_t)grow * ldadd + gcol);
                const float4 d1 = *reinterpret_cast<const float4*>(ADDp + (size_t)grow * ldadd + gcol + 4);
                o0.x = fmaf(sign, acc[i][0], d0.x);
                o0.y = fmaf(sign, acc[i][1], d0.y);
                o0.z = fmaf(sign, acc[i][2], d0.z);
                o0.w = fmaf(sign, acc[i][3], d0.w);
                o1.x = fmaf(sign, acc[i][4], d1.x);
                o1.y = fmaf(sign, acc[i][5], d1.y);
                o1.z = fmaf(sign, acc[i][6], d1.z);
                o1.w = fmaf(sign, acc[i][7], d1.w);
            } else {
                o0.x = sign * acc[i][0];
                o0.y = sign * acc[i][1];
                o0.z = sign * acc[i][2];
                o0.w = sign * acc[i][3];
                o1.x = sign * acc[i][4];
                o1.y = sign * acc[i][5];
                o1.z = sign * acc[i][6];
                o1.w = sign * acc[i][7];
            }
            *reinterpret_cast<float4*>(Cp + (size_t)grow * ldc + gcol)     = o0;
            *reinterpret_cast<float4*>(Cp + (size_t)grow * ldc + gcol + 4) = o1;
        } else {
#pragma unroll
            for (int j = 0; j < 8; ++j) {
                const int gc = gcol + j;
                if (gc < N) {
                    const float add = ADDp ? ADDp[(size_t)grow * ldadd + gc] : 0.f;
                    Cp[(size_t)grow * ldc + gc] = fmaf(sign, acc[i][j], add);
                }
            }
        }
    }
}

// ===========================================================================
// Split-bf16 MFMA GEMM: C = ADD + sign * (A @ Bt^T)
//   A: [M,K] bf16 hi/lo (lda shorts); Bt: [N,K] bf16 hi/lo (ldb shorts)
//   i.e. C[m][n] = sum_k A[m][k]*Bt[n][k]. M,N %128==0, K %64==0.
// Tile 128x128, BK=64, 4 waves each owning 64x64 (4x4 of 16x16 mfma tiles).
// acc += ah*bh + ah*bl + al*bh (al*bl dropped, ~2^-18 rel).
// mfma_f32_16x16x32_bf16 layouts: A/B lane l: idx (l&15), k=(l>>4)*8+j
// (contiguous 8 shorts -> one ds_read_b128); D: col=l&15, row=(l>>4)*4+reg.
// LDS rows padded to 72 shorts (144B) -> all 32 banks busy on frag reads.
// ===========================================================================
template <bool HAS_ADD>
__global__ __launch_bounds__(256) void gemm_bf16s(
    float* __restrict__ Cp, int ldc,
    const unsigned short* __restrict__ Ahi, const unsigned short* __restrict__ Alo, int lda,
    const unsigned short* __restrict__ Bhi, const unsigned short* __restrict__ Blo, int ldb,
    const float* __restrict__ ADDp, int ldadd,
    int M, int N, int K, float sign)
{
    __shared__ unsigned short As[2][128][72];  // [hi/lo][m][k]
    __shared__ unsigned short Bs[2][128][72];  // [hi/lo][n][k]

    const int tid  = threadIdx.x;
    const int wave = tid >> 6, lane = tid & 63;
    const int l15  = lane & 15, lk = lane >> 4;      // lk 0..3
    const int wr   = (wave >> 1) * 64, wc = (wave & 1) * 64;
    const int row0 = blockIdx.y * 128, col0 = blockIdx.x * 128;

    f32x4 acc[4][4] = {};

    for (int k0 = 0; k0 < K; k0 += 64) {
#pragma unroll
        for (int i = 0; i < 4; ++i) {
            const int f  = tid + i * 256;       // 0..1023
            const int r  = f >> 3;              // 0..127
            const int cg = (f & 7) * 8;         // short offset, 16B units
            const size_t ga = (size_t)(row0 + r) * lda + k0 + cg;
            *reinterpret_cast<uint4*>(&As[0][r][cg]) = *reinterpret_cast<const uint4*>(&Ahi[ga]);
            *reinterpret_cast<uint4*>(&As[1][r][cg]) = *reinterpret_cast<const uint4*>(&Alo[ga]);
            const size_t gb = (size_t)(col0 + r) * ldb + k0 + cg;
            *reinterpret_cast<uint4*>(&Bs[0][r][cg]) = *reinterpret_cast<const uint4*>(&Bhi[gb]);
            *reinterpret_cast<uint4*>(&Bs[1][r][cg]) = *reinterpret_cast<const uint4*>(&Blo[gb]);
        }
        __syncthreads();
#pragma unroll
        for (int ks = 0; ks < 2; ++ks) {
            const int kb = ks * 32 + lk * 8;
            bf16x8 ah[4], al[4], bh[4], bl[4];
#pragma unroll
            for (int mi = 0; mi < 4; ++mi) {
                ah[mi] = *reinterpret_cast<const bf16x8*>(&As[0][wr + mi * 16 + l15][kb]);
                al[mi] = *reinterpret_cast<const bf16x8*>(&As[1][wr + mi * 16 + l15][kb]);
                bh[mi] = *reinterpret_cast<const bf16x8*>(&Bs[0][wc + mi * 16 + l15][kb]);
                bl[mi] = *reinterpret_cast<const bf16x8*>(&Bs[1][wc + mi * 16 + l15][kb]);
            }
#pragma unroll
            for (int mi = 0; mi < 4; ++mi)
#pragma unroll
                for (int nj = 0; nj < 4; ++nj) {
                    acc[mi][nj] = __builtin_amdgcn_mfma_f32_16x16x32_bf16(ah[mi], bh[nj], acc[mi][nj], 0, 0, 0);
                    acc[mi][nj] = __builtin_amdgcn_mfma_f32_16x16x32_bf16(ah[mi], bl[nj], acc[mi][nj], 0, 0, 0);
                    acc[mi][nj] = __builtin_amdgcn_mfma_f32_16x16x32_bf16(al[mi], bh[nj], acc[mi][nj], 0, 0, 0);
                }
        }
        __syncthreads();
    }

#pragma unroll
    for (int mi = 0; mi < 4; ++mi)
#pragma unroll
        for (int nj = 0; nj < 4; ++nj)
#pragma unroll
            for (int rr = 0; rr < 4; ++rr) {
                const int gr = row0 + wr + mi * 16 + lk * 4 + rr;
                const int gc = col0 + wc + nj * 16 + l15;
                float v = sign * acc[mi][nj][rr];
                if (HAS_ADD) v += ADDp[(size_t)gr * ldadd + gc];
                Cp[(size_t)gr * ldc + gc] = v;
            }
}

// ===========================================================================
// fp32 [R,C] (ldi) -> bf16 hi/lo [R,C] (ldo). C%4==0.
// ===========================================================================
__global__ void cvt_split_kernel(const float* __restrict__ in, int ldi,
                                 unsigned short* __restrict__ oh,
                                 unsigned short* __restrict__ ol, int ldo,
                                 int R, int Cq)
{
    const int total = R * Cq;
    for (int idx = blockIdx.x * blockDim.x + threadIdx.x; idx < total;
         idx += gridDim.x * blockDim.x) {
        const int r  = idx / Cq;
        const int c  = (idx - r * Cq) * 4;
        const float4 v = *reinterpret_cast<const float4*>(in + (size_t)r * ldi + c);
        const float vv[4] = {v.x, v.y, v.z, v.w};
        ushort4 h, l;
        unsigned short hs[4], ls[4];
#pragma unroll
        for (int j = 0; j < 4; ++j) {
            __bf16 b  = (__bf16)vv[j];
            __bf16 lo = (__bf16)(vv[j] - (float)b);
            hs[j] = __builtin_bit_cast(unsigned short, b);
            ls[j] = __builtin_bit_cast(unsigned short, lo);
        }
        h.x = hs[0]; h.y = hs[1]; h.z = hs[2]; h.w = hs[3];
        l.x = ls[0]; l.y = ls[1]; l.z = ls[2]; l.w = ls[3];
        *reinterpret_cast<ushort4*>(oh + (size_t)r * ldo + c) = h;
        *reinterpret_cast<ushort4*>(ol + (size_t)r * ldo + c) = l;
    }
}

// ===========================================================================
// fp32 [R,C] (ldi) -> transposed bf16 hi/lo [C,R] (ldo). R,C %32==0.
// ===========================================================================
__global__ __launch_bounds__(256) void cvt_split_t_kernel(
    const float* __restrict__ in, int ldi,
    unsigned short* __restrict__ oh, unsigned short* __restrict__ ol, int ldo,
    int R, int C)
{
    __shared__ float Ts[32][33];
    const int tx = threadIdx.x & 31, ty = threadIdx.x >> 5;
    const int c0 = blockIdx.x * 32, r0 = blockIdx.y * 32;
#pragma unroll
    for (int i = 0; i < 4; ++i) {
        const int r = ty + i * 8;
        Ts[r][tx] = in[(size_t)(r0 + r) * ldi + c0 + tx];
    }
    __syncthreads();
#pragma unroll
    for (int i = 0; i < 4; ++i) {
        const int c = ty + i * 8;
        const float v = Ts[tx][c];
        __bf16 b  = (__bf16)v;
        __bf16 lo = (__bf16)(v - (float)b);
        const size_t o = (size_t)(c0 + c) * ldo + r0 + tx;
        oh[o] = __builtin_bit_cast(unsigned short, b);
        ol[o] = __builtin_bit_cast(unsigned short, lo);
    }
}

// ===========================================================================
// Gauss-Jordan helpers (Sinv, 512x512 via 8x 64-blocks)
// ===========================================================================
__global__ __launch_bounds__(256) void inv64_kernel(
    const float* __restrict__ W, int ldw, int kb, float* __restrict__ Dinv)
{
    __shared__ float T[64][129];
    __shared__ float multcol[64];
    const int tid = threadIdx.x;

    for (int idx = tid; idx < 64 * 64; idx += 256) {
        const int r = idx >> 6, c = idx & 63;
        T[r][c]      = W[(size_t)(kb * 64 + r) * ldw + kb * 64 + c];
        T[r][64 + c] = (r == c) ? 1.f : 0.f;
    }
    __syncthreads();

    for (int p = 0; p < 64; ++p) {
        const float rp = 1.f / T[p][p];
        __syncthreads();
        if (tid < 128) T[p][tid] *= rp;
        if (tid >= 128 && tid < 192) multcol[tid - 128] = T[tid - 128][p];
        __syncthreads();
        for (int idx = tid; idx < 64 * 128; idx += 256) {
            const int r = idx >> 7, c = idx & 127;
            if (r != p) T[r][c] = fmaf(-multcol[r], T[p][c], T[r][c]);
        }
        __syncthreads();
    }

    for (int idx = tid; idx < 64 * 64; idx += 256) {
        const int r = idx >> 6, c = idx & 63;
        Dinv[idx] = T[r][64 + c];
    }
}

// W[pivot rows, 64-col slice] = Dinv @ W[pivot rows, slice], in place. grid 16.
__global__ __launch_bounds__(256) void scale_rows_kernel(
    float* __restrict__ W, const float* __restrict__ Dinv, int kb)
{
    __shared__ float Dl[64][65];
    __shared__ float Ws[64][65];
    const int tid = threadIdx.x;
    const int cb  = blockIdx.x * 64;
    for (int i = tid; i < 4096; i += 256) Dl[i >> 6][i & 63] = Dinv[i];
    for (int i = tid; i < 4096; i += 256) {
        const int r = i >> 6, c = i & 63;
        Ws[r][c] = W[(size_t)(kb * 64 + r) * 1024 + cb + c];
    }
    __syncthreads();
    const int c = tid & 63, rg = tid >> 6;
#pragma unroll
    for (int i = 0; i < 16; ++i) {
        const int r = rg * 16 + i;
        float s = 0.f;
#pragma unroll 8
        for (int j = 0; j < 64; ++j) s = fmaf(Dl[r][j], Ws[j][c], s);
        W[(size_t)(kb * 64 + r) * 1024 + cb + c] = s;
    }
}

__global__ void init_eye_kernel(float* __restrict__ W)
{
    const int idx = blockIdx.x * 256 + threadIdx.x;
    if (idx < 512 * 512) {
        const int r = idx >> 9, c = idx & 511;
        W[(size_t)r * 1024 + 512 + c] = (r == c) ? 1.f : 0.f;
    }
}

__global__ void multcopy_kernel(const float* __restrict__ W, float* __restrict__ Mbuf, int kb)
{
    const int idx = blockIdx.x * 256 + threadIdx.x;
    if (idx < 512 * 64) {
        const int r = idx >> 6, c = idx & 63;
        const float v = W[(size_t)r * 1024 + kb * 64 + c];
        Mbuf[idx] = ((r >> 6) == kb) ? 0.f : v;
    }
}

// ===========================================================================
// host-side launch
// ===========================================================================
static void run_gj_inverse(float* W, float* Mbuf, float* Dinv, hipStream_t stream,
                           bool fast_scale)
{
    const dim3 blk(256);
    for (int kb = 0; kb < 8; ++kb) {
        inv64_kernel<<<dim3(1), blk, 0, stream>>>(W, 1024, kb, Dinv);
        if (fast_scale) {
            scale_rows_kernel<<<dim3(16), blk, 0, stream>>>(W, Dinv, kb);
        } else {
            gemm_f32<false><<<dim3(1024 / 128, 1), blk, 0, stream>>>(
                W + (size_t)kb * 64 * 1024, 1024, Dinv, 64,
                W + (size_t)kb * 64 * 1024, 1024, nullptr, 0, 64, 1024, 64, 1.f);
        }
        multcopy_kernel<<<dim3((512 * 64) / 256), blk, 0, stream>>>(W, Mbuf, kb);
        gemm_f32<false><<<dim3(1024 / 128, 512 / 128), blk, 0, stream>>>(
            W, 1024, Mbuf, 64, W + (size_t)kb * 64 * 1024, 1024,
            W, 1024, 512, 1024, 64, -1.f);
    }
}

static void run_fp32_path(void* const* d_in, void* d_out, void* d_ws, hipStream_t stream)
{
    const float* state   = (const float*)d_in[0];
    const float* cov     = (const float*)d_in[1];
    const float* meas    = (const float*)d_in[2];
    const float* control = (const float*)d_in[3];
    const float* F       = (const float*)d_in[4];
    const float* Q       = (const float*)d_in[5];
    const float* Bc      = (const float*)d_in[6];
    const float* H       = (const float*)d_in[7];
    const float* R       = (const float*)d_in[8];

    float* out_state = (float*)d_out;
    float* out_cov   = out_state + (size_t)Dd * Bb;
    float* T1        = out_cov;

    float* ws    = (float*)d_ws;
    float* cov_p = ws;  ws += (size_t)Dd * Dd;
    float* HCP   = ws;  ws += (size_t)Mm * Dd;
    float* W     = ws;  ws += (size_t)Mm * 1024;
    float* Mbuf  = ws;  ws += (size_t)Mm * 64;
    float* Dinv  = ws;  ws += 64 * 64;
    float* Kg    = ws;  ws += (size_t)Dd * Mm;
    float* KHI   = ws;  ws += (size_t)Dd * Dd;

    const dim3 blk(256);
    gemm_f32<false><<<dim3(Dd / 128, Dd / 128), blk, 0, stream>>>(
        T1, Dd, F, Dd, cov, Dd, nullptr, 0, Dd, Dd, Dd, 1.f);
    gemm_f32<true><<<dim3(Dd / 128, Dd / 128), blk, 0, stream>>>(
        cov_p, Dd, T1, Dd, F, Dd, Q, Dd, Dd, Dd, Dd, 1.f);
    gemm_f32<false><<<dim3(Dd / 128, Mm / 128), blk, 0, stream>>>(
        HCP, Dd, H, Dd, cov_p, Dd, nullptr, 0, Mm, Dd, Dd, 1.f);
    gemm_f32<true><<<dim3(Mm / 128, Mm / 128), blk, 0, stream>>>(
        W, 1024, HCP, Dd, H, Dd, R, Mm, Mm, Mm, Dd, 1.f);
    init_eye_kernel<<<dim3((512 * 512) / 256), blk, 0, stream>>>(W);
    run_gj_inverse(W, Mbuf, Dinv, stream, false);
    float* Sinv = W + 512;
    gemm_f32<true><<<dim3(Mm / 128, Dd / 128), blk, 0, stream>>>(
        HCP, Mm, cov_p, Dd, H, Dd, nullptr, 0, Dd, Mm, Dd, 1.f);
    gemm_f32<false><<<dim3(Mm / 128, Dd / 128), blk, 0, stream>>>(
        Kg, Mm, HCP, Mm, Sinv, 1024, nullptr, 0, Dd, Mm, Mm, 1.f);
    gemm_f32<false><<<dim3(Dd / 128, Dd / 128), blk, 0, stream>>>(
        KHI, Dd, Kg, Mm, H, Dd, nullptr, 0, Dd, Dd, Mm, 1.f);
    gemm_f32<false><<<dim3(Dd / 128, Dd / 128), blk, 0, stream>>>(
        out_cov, Dd, KHI, Dd, cov_p, Dd, cov_p, Dd, Dd, Dd, Dd, -1.f);
    gemm_f32<false><<<dim3(Bb / 128, Dd / 128), blk, 0, stream>>>(
        out_state, Bb, F, Dd, state, Bb, nullptr, 0, Dd, Bb, Dd, 1.f);
    gemm_f32<false><<<dim3(Bb / 128, Dd / 128), blk, 0, stream>>>(
        out_state, Bb, Bc, Cc, control, Bb, out_state, Bb, Dd, Bb, Cc, 1.f);
    for (int b0 = 0; b0 < Bb; b0 += 2048) {
        float* innov_c = KHI;
        gemm_f32<false><<<dim3(2048 / 128, Mm / 128), blk, 0, stream>>>(
            innov_c, 2048, H, Dd, out_state + b0, Bb, meas + b0, Bb,
            Mm, 2048, Dd, -1.f);
        gemm_f32<false><<<dim3(2048 / 128, Dd / 128), blk, 0, stream>>>(
            out_state + b0, Bb, Kg, Mm, innov_c, 2048, out_state + b0, Bb,
            Dd, 2048, Mm, 1.f);
    }
}

extern "C" void kernel_launch(void* const* d_in, const int* in_sizes, int n_in,
                              void* d_out, int out_size, void* d_ws, size_t ws_size,
                              hipStream_t stream)
{
    // fast path needs ~64.2 MB of scratch
    if (ws_size < 68000000ull) { run_fp32_path(d_in, d_out, d_ws, stream); return; }

    const float* state   = (const float*)d_in[0];
    const float* cov     = (const float*)d_in[1];   // symmetric
    const float* meas    = (const float*)d_in[2];
    const float* control = (const float*)d_in[3];
    const float* F       = (const float*)d_in[4];
    const float* Q       = (const float*)d_in[5];
    const float* Bc      = (const float*)d_in[6];
    const float* H       = (const float*)d_in[7];
    const float* R       = (const float*)d_in[8];

    float* out_state = (float*)d_out;
    float* out_cov   = out_state + (size_t)Dd * Bb;   // holds T1 fp32 early

    // ---- workspace arena ----
    size_t off = 0;
    auto alloc = [&](size_t bytes) {
        void* p = (char*)d_ws + off;
        off = (off + bytes + 255) & ~(size_t)255;
        return p;
    };
    float* covp  = (float*)alloc(4194304);             // cov_p fp32
    float* W     = (float*)alloc(2097152);             // augmented [S|I]
    float* Mbuf  = (float*)alloc(131072);
    float* Dinv  = (float*)alloc(16384);
    float* Kgf   = (float*)alloc(2097152);             // Kg fp32
    float* mdbuf = (float*)alloc(2097152);             // HC / PHT fp32
    float* big   = (float*)alloc(8388608);             // KH fp32 / innov chunk
    typedef unsigned short us;
    us* FBc_h   = (us*)alloc(2621440);  us* FBc_l   = (us*)alloc(2621440);  // [1024,1280]
    us* bt1_h   = (us*)alloc(2097152);  us* bt1_l   = (us*)alloc(2097152);  // cov_hl -> covp_hl
    us* bt2_h   = (us*)alloc(2097152);  us* bt2_l   = (us*)alloc(2097152);  // T1_hl -> covpT_hl
    us* H_h     = (us*)alloc(1048576);  us* H_l     = (us*)alloc(1048576);  // [512,1024]
    us* HT_h    = (us*)alloc(1048576);  us* HT_l    = (us*)alloc(1048576);  // [1024,512]
    us* amh_h   = (us*)alloc(1048576);  us* amh_l   = (us*)alloc(1048576);  // HC_hl -> PHT_hl
    us* SvT_h   = (us*)alloc(524288);   us* SvT_l   = (us*)alloc(524288);   // [512,512]
    us* Kg_h    = (us*)alloc(1048576);  us* Kg_l    = (us*)alloc(1048576);  // [1024,512]
    us* KH_h    = (us*)alloc(2097152);  us* KH_l    = (us*)alloc(2097152);  // [1024,1024]
    us* ar_h    = (us*)alloc(10485760); us* ar_l    = (us*)alloc(10485760); // [4096,1280]

    const dim3 blk(256);
    auto cvt = [&](const float* in, int ldi, us* oh, us* ol, int ldo, int Rr, int Cc_) {
        const int total4 = Rr * (Cc_ / 4);
        const int grid = min(4096, (total4 + 255) / 256);
        cvt_split_kernel<<<dim3(grid), blk, 0, stream>>>(in, ldi, oh, ol, ldo, Rr, Cc_ / 4);
    };
    auto cvtT = [&](const float* in, int ldi, us* oh, us* ol, int ldo, int Rr, int Cc_) {
        cvt_split_t_kernel<<<dim3(Cc_ / 32, Rr / 32), blk, 0, stream>>>(in, ldi, oh, ol, ldo, Rr, Cc_);
    };
    auto mm = [&](float* C, int ldc, const us* Ah, const us* Al, int lda,
                  const us* Bh, const us* Bl, int ldb, const float* ADD, int ldadd,
                  int M, int N, int K, float sign) {
        if (ADD)
            gemm_bf16s<true><<<dim3(N / 128, M / 128), blk, 0, stream>>>(
                C, ldc, Ah, Al, lda, Bh, Bl, ldb, ADD, ldadd, M, N, K, sign);
        else
            gemm_bf16s<false><<<dim3(N / 128, M / 128), blk, 0, stream>>>(
                C, ldc, Ah, Al, lda, Bh, Bl, ldb, nullptr, 0, M, N, K, sign);
    };

    // ---- operand conversions ----
    cvt(F, 1024, FBc_h, FBc_l, 1280, 1024, 1024);          // FBc cols 0..1023
    cvt(Bc, 256, FBc_h + 1024, FBc_l + 1024, 1280, 1024, 256);  // cols 1024..1279
    cvt(cov, 1024, bt1_h, bt1_l, 1024, 1024, 1024);        // cov (symmetric) as Bt
    cvt(H, 1024, H_h, H_l, 1024, 512, 1024);               // H row-major (A-form & Bt-form)
    cvtT(H, 1024, HT_h, HT_l, 512, 512, 1024);             // H^T as Bt for KH

    // ---- covariance chain ----
    // T1 = F @ cov   (Bt = cov, symmetric)  -> out_cov (fp32, temporary)
    mm(out_cov, 1024, FBc_h, FBc_l, 1280, bt1_h, bt1_l, 1024, nullptr, 0, 1024, 1024, 1024, 1.f);
    cvt(out_cov, 1024, bt2_h, bt2_l, 1024, 1024, 1024);    // T1_hl
    // cov_p = T1 @ F^T + Q   (Bt = F rows = FBc cols 0..1023)
    mm(covp, 1024, bt2_h, bt2_l, 1024, FBc_h, FBc_l, 1280, Q, 1024, 1024, 1024, 1024, 1.f);
    cvt(covp, 1024, bt1_h, bt1_l, 1024, 1024, 1024);       // covp_hl (A-form)
    cvtT(covp, 1024, bt2_h, bt2_l, 1024, 1024, 1024);      // covpT_hl (Bt-form)
    // HC = H @ cov_p
    mm(mdbuf, 1024, H_h, H_l, 1024, bt2_h, bt2_l, 1024, nullptr, 0, 512, 1024, 1024, 1.f);
    cvt(mdbuf, 1024, amh_h, amh_l, 1024, 512, 1024);       // HC_hl
    // S = HC @ H^T + R  -> left half of W
    mm(W, 1024, amh_h, amh_l, 1024, H_h, H_l, 1024, R, 512, 512, 512, 1024, 1.f);
    init_eye_kernel<<<dim3((512 * 512) / 256), blk, 0, stream>>>(W);
    run_gj_inverse(W, Mbuf, Dinv, stream, true);
    cvtT(W + 512, 1024, SvT_h, SvT_l, 512, 512, 512);      // Sinv^T as Bt
    // PHT = cov_p @ H^T
    mm(mdbuf, 512, bt1_h, bt1_l, 1024, H_h, H_l, 1024, nullptr, 0, 1024, 512, 1024, 1.f);
    cvt(mdbuf, 512, amh_h, amh_l, 512, 1024, 512);         // PHT_hl
    // Kg = PHT @ Sinv
    mm(Kgf, 512, amh_h, amh_l, 512, SvT_h, SvT_l, 512, nullptr, 0, 1024, 512, 512, 1.f);
    cvt(Kgf, 512, Kg_h, Kg_l, 512, 1024, 512);             // Kg_hl
    // KH = Kg @ H   (Bt = H^T)
    mm(big, 1024, Kg_h, Kg_l, 512, HT_h, HT_l, 512, nullptr, 0, 1024, 1024, 512, 1.f);
    cvt(big, 1024, KH_h, KH_l, 1024, 1024, 1024);          // KH_hl
    // cov_n = cov_p - KH @ cov_p
    mm(out_cov, 1024, KH_h, KH_l, 1024, bt2_h, bt2_l, 1024, covp, 1024, 1024, 1024, 1024, -1.f);

    // ---- state chain, 2 chunks of 4096 columns ----
    for (int b0 = 0; b0 < Bb; b0 += 4096) {
        // BtExt = [state^T | control^T] packed [4096,1280]
        cvtT(state + b0, 8192, ar_h, ar_l, 1280, 1024, 4096);
        cvtT(control + b0, 8192, ar_h + 1024, ar_l + 1024, 1280, 256, 4096);
        // state_p = [F|Bc] @ [state;control]
        mm(out_state + b0, 8192, FBc_h, FBc_l, 1280, ar_h, ar_l, 1280,
           nullptr, 0, 1024, 4096, 1280, 1.f);
        // innov = meas - H @ state_p
        cvtT(out_state + b0, 8192, ar_h, ar_l, 1024, 1024, 4096);
        mm(big, 4096, H_h, H_l, 1024, ar_h, ar_l, 1024, meas + b0, 8192,
           512, 4096, 1024, -1.f);
        // state_n = state_p + Kg @ innov
        cvtT(big, 4096, ar_h, ar_l, 512, 512, 4096);
        mm(out_state + b0, 8192, Kg_h, Kg_l, 512, ar_h, ar_l, 512,
           out_state + b0, 8192, 1024, 4096, 512, 1.f);
    }
}

// Round 4
// 2029.126 us; speedup vs baseline: 2.0553x; 1.5585x over previous
//
#include <hip/hip_runtime.h>

// Kalman filter fused step. D=1024, M=512, C=256, B=8192, fp32 in/out.
// Fast path: split-bf16 (hi+lo) MFMA GEMMs + Newton-Schulz matrix inverse.
// Fallback (ws_size too small): fp32 vector-ALU path with blocked GJ inverse.

static constexpr int Dd = 1024;
static constexpr int Mm = 512;
static constexpr int Cc = 256;
static constexpr int Bb = 8192;

typedef __bf16 bf16x8 __attribute__((ext_vector_type(8)));
typedef float f32x4 __attribute__((ext_vector_type(4)));
typedef unsigned short us;

// ===========================================================================
// fp32 tiled GEMM (fallback path): C = ADD + sign*(A@opB)
// ===========================================================================
template <bool TRANSB>
__global__ __launch_bounds__(256) void gemm_f32(
    float* __restrict__ Cp, int ldc,
    const float* __restrict__ Ap, int lda,
    const float* __restrict__ Bp, int ldb,
    const float* __restrict__ ADDp, int ldadd,
    int M, int N, int K, float sign)
{
    __shared__ float As[16][132];
    __shared__ float Bs[16][132];

    const int tid  = threadIdx.x;
    const int row0 = blockIdx.y * 128;
    const int col0 = blockIdx.x * 128;
    const int tr   = tid >> 4;
    const int tc   = tid & 15;

    float acc[8][8];
#pragma unroll
    for (int i = 0; i < 8; ++i)
#pragma unroll
        for (int j = 0; j < 8; ++j) acc[i][j] = 0.f;

    for (int k0 = 0; k0 < K; k0 += 16) {
#pragma unroll
        for (int l = 0; l < 2; ++l) {
            const int f    = tid + l * 256;
            const int r    = f >> 2;
            const int kq   = (f & 3) << 2;
            const int grow = row0 + r;
            float4 v = make_float4(0.f, 0.f, 0.f, 0.f);
            if (grow < M)
                v = *reinterpret_cast<const float4*>(Ap + (size_t)grow * lda + k0 + kq);
            As[kq + 0][r] = v.x;
            As[kq + 1][r] = v.y;
            As[kq + 2][r] = v.z;
            As[kq + 3][r] = v.w;
        }
        if (!TRANSB) {
#pragma unroll
            for (int l = 0; l < 2; ++l) {
                const int f    = tid + l * 256;
                const int kk   = f >> 5;
                const int cq   = (f & 31) << 2;
                const int gcol = col0 + cq;
                float4 v = make_float4(0.f, 0.f, 0.f, 0.f);
                if (gcol + 3 < N)
                    v = *reinterpret_cast<const float4*>(Bp + (size_t)(k0 + kk) * ldb + gcol);
                *reinterpret_cast<float4*>(&Bs[kk][cq]) = v;
            }
        } else {
#pragma unroll
            for (int l = 0; l < 2; ++l) {
                const int f    = tid + l * 256;
                const int n    = f >> 2;
                const int kq   = (f & 3) << 2;
                const int gcol = col0 + n;
                float4 v = make_float4(0.f, 0.f, 0.f, 0.f);
                if (gcol < N)
                    v = *reinterpret_cast<const float4*>(Bp + (size_t)gcol * ldb + k0 + kq);
                Bs[kq + 0][n] = v.x;
                Bs[kq + 1][n] = v.y;
                Bs[kq + 2][n] = v.z;
                Bs[kq + 3][n] = v.w;
            }
        }
        __syncthreads();

#pragma unroll
        for (int kk = 0; kk < 16; ++kk) {
            const float4 a0 = *reinterpret_cast<const float4*>(&As[kk][tr * 8]);
            const float4 a1 = *reinterpret_cast<const float4*>(&As[kk][tr * 8 + 4]);
            const float4 b0 = *reinterpret_cast<const float4*>(&Bs[kk][tc * 8]);
            const float4 b1 = *reinterpret_cast<const float4*>(&Bs[kk][tc * 8 + 4]);
            const float a_frag[8] = {a0.x, a0.y, a0.z, a0.w, a1.x, a1.y, a1.z, a1.w};
            const float b_frag[8] = {b0.x, b0.y, b0.z, b0.w, b1.x, b1.y, b1.z, b1.w};
#pragma unroll
            for (int i = 0; i < 8; ++i)
#pragma unroll
                for (int j = 0; j < 8; ++j)
                    acc[i][j] = fmaf(a_frag[i], b_frag[j], acc[i][j]);
        }
        __syncthreads();
    }

#pragma unroll
    for (int i = 0; i < 8; ++i) {
        const int grow = row0 + tr * 8 + i;
        if (grow >= M) continue;
        const int gcol = col0 + tc * 8;
#pragma unroll
        for (int j = 0; j < 8; ++j) {
            const int gc = gcol + j;
            if (gc < N) {
                const float add = ADDp ? ADDp[(size_t)grow * ldadd + gc] : 0.f;
                Cp[(size_t)grow * ldc + gc] = fmaf(sign, acc[i][j], add);
            }
        }
    }
}

// ===========================================================================
// Split-bf16 MFMA GEMM: C = addscale*ADD + sign * (A @ Bt^T)
//   A: [M,K] bf16 hi/lo (lda shorts); Bt: [N,K] bf16 hi/lo (ldb shorts)
//   M,N %128==0, K %64==0. Tile 128x128, BK=64, 4 waves each 64x64.
// acc += ah*bh + ah*bl + al*bh (al*bl dropped, ~2^-16 rel).
// ===========================================================================
template <bool HAS_ADD>
__global__ __launch_bounds__(256) void gemm_bf16s(
    float* __restrict__ Cp, int ldc,
    const us* __restrict__ Ahi, const us* __restrict__ Alo, int lda,
    const us* __restrict__ Bhi, const us* __restrict__ Blo, int ldb,
    const float* __restrict__ ADDp, int ldadd,
    int M, int N, int K, float sign, float addscale)
{
    __shared__ us As[2][128][72];  // [hi/lo][m][k]
    __shared__ us Bs[2][128][72];  // [hi/lo][n][k]

    const int tid  = threadIdx.x;
    const int wave = tid >> 6, lane = tid & 63;
    const int l15  = lane & 15, lk = lane >> 4;
    const int wr   = (wave >> 1) * 64, wc = (wave & 1) * 64;
    const int row0 = blockIdx.y * 128, col0 = blockIdx.x * 128;

    f32x4 acc[4][4] = {};

    for (int k0 = 0; k0 < K; k0 += 64) {
#pragma unroll
        for (int i = 0; i < 4; ++i) {
            const int f  = tid + i * 256;
            const int r  = f >> 3;
            const int cg = (f & 7) * 8;
            const size_t ga = (size_t)(row0 + r) * lda + k0 + cg;
            *reinterpret_cast<uint4*>(&As[0][r][cg]) = *reinterpret_cast<const uint4*>(&Ahi[ga]);
            *reinterpret_cast<uint4*>(&As[1][r][cg]) = *reinterpret_cast<const uint4*>(&Alo[ga]);
            const size_t gb = (size_t)(col0 + r) * ldb + k0 + cg;
            *reinterpret_cast<uint4*>(&Bs[0][r][cg]) = *reinterpret_cast<const uint4*>(&Bhi[gb]);
            *reinterpret_cast<uint4*>(&Bs[1][r][cg]) = *reinterpret_cast<const uint4*>(&Blo[gb]);
        }
        __syncthreads();
#pragma unroll
        for (int ks = 0; ks < 2; ++ks) {
            const int kb = ks * 32 + lk * 8;
            bf16x8 ah[4], al[4], bh[4], bl[4];
#pragma unroll
            for (int mi = 0; mi < 4; ++mi) {
                ah[mi] = *reinterpret_cast<const bf16x8*>(&As[0][wr + mi * 16 + l15][kb]);
                al[mi] = *reinterpret_cast<const bf16x8*>(&As[1][wr + mi * 16 + l15][kb]);
                bh[mi] = *reinterpret_cast<const bf16x8*>(&Bs[0][wc + mi * 16 + l15][kb]);
                bl[mi] = *reinterpret_cast<const bf16x8*>(&Bs[1][wc + mi * 16 + l15][kb]);
            }
#pragma unroll
            for (int mi = 0; mi < 4; ++mi)
#pragma unroll
                for (int nj = 0; nj < 4; ++nj) {
                    acc[mi][nj] = __builtin_amdgcn_mfma_f32_16x16x32_bf16(ah[mi], bh[nj], acc[mi][nj], 0, 0, 0);
                    acc[mi][nj] = __builtin_amdgcn_mfma_f32_16x16x32_bf16(ah[mi], bl[nj], acc[mi][nj], 0, 0, 0);
                    acc[mi][nj] = __builtin_amdgcn_mfma_f32_16x16x32_bf16(al[mi], bh[nj], acc[mi][nj], 0, 0, 0);
                }
        }
        __syncthreads();
    }

#pragma unroll
    for (int mi = 0; mi < 4; ++mi)
#pragma unroll
        for (int nj = 0; nj < 4; ++nj)
#pragma unroll
            for (int rr = 0; rr < 4; ++rr) {
                const int gr = row0 + wr + mi * 16 + lk * 4 + rr;
                const int gc = col0 + wc + nj * 16 + l15;
                float v = sign * acc[mi][nj][rr];
                if (HAS_ADD) v = fmaf(addscale, ADDp[(size_t)gr * ldadd + gc], v);
                Cp[(size_t)gr * ldc + gc] = v;
            }
}

// ===========================================================================
// fp32 [R,C] (ldi) -> bf16 hi/lo [R,C] (ldo). C%4==0.
// ===========================================================================
__global__ void cvt_split_kernel(const float* __restrict__ in, int ldi,
                                 us* __restrict__ oh, us* __restrict__ ol, int ldo,
                                 int R, int Cq)
{
    const int total = R * Cq;
    for (int idx = blockIdx.x * blockDim.x + threadIdx.x; idx < total;
         idx += gridDim.x * blockDim.x) {
        const int r  = idx / Cq;
        const int c  = (idx - r * Cq) * 4;
        const float4 v = *reinterpret_cast<const float4*>(in + (size_t)r * ldi + c);
        const float vv[4] = {v.x, v.y, v.z, v.w};
        ushort4 h, l;
        unsigned short hs[4], ls[4];
#pragma unroll
        for (int j = 0; j < 4; ++j) {
            __bf16 b  = (__bf16)vv[j];
            __bf16 lo = (__bf16)(vv[j] - (float)b);
            hs[j] = __builtin_bit_cast(unsigned short, b);
            ls[j] = __builtin_bit_cast(unsigned short, lo);
        }
        h.x = hs[0]; h.y = hs[1]; h.z = hs[2]; h.w = hs[3];
        l.x = ls[0]; l.y = ls[1]; l.z = ls[2]; l.w = ls[3];
        *reinterpret_cast<ushort4*>(oh + (size_t)r * ldo + c) = h;
        *reinterpret_cast<ushort4*>(ol + (size_t)r * ldo + c) = l;
    }
}

// ===========================================================================
// fp32 [R,C] (ldi) -> transposed bf16 hi/lo [C,R] (ldo). R,C %32==0.
// ===========================================================================
__global__ __launch_bounds__(256) void cvt_split_t_kernel(
    const float* __restrict__ in, int ldi,
    us* __restrict__ oh, us* __restrict__ ol, int ldo,
    int R, int C)
{
    __shared__ float Ts[32][33];
    const int tx = threadIdx.x & 31, ty = threadIdx.x >> 5;
    const int c0 = blockIdx.x * 32, r0 = blockIdx.y * 32;
#pragma unroll
    for (int i = 0; i < 4; ++i) {
        const int r = ty + i * 8;
        Ts[r][tx] = in[(size_t)(r0 + r) * ldi + c0 + tx];
    }
    __syncthreads();
#pragma unroll
    for (int i = 0; i < 4; ++i) {
        const int c = ty + i * 8;
        const float v = Ts[tx][c];
        __bf16 b  = (__bf16)v;
        __bf16 lo = (__bf16)(v - (float)b);
        const size_t o = (size_t)(c0 + c) * ldo + r0 + tx;
        oh[o] = __builtin_bit_cast(unsigned short, b);
        ol[o] = __builtin_bit_cast(unsigned short, lo);
    }
}

// ===========================================================================
// fp32 [R,C] -> BOTH normal hi/lo [R,C] (ldn) and transposed hi/lo [C,R] (ldt)
// ===========================================================================
__global__ __launch_bounds__(256) void cvt_split_both_kernel(
    const float* __restrict__ in, int ldi,
    us* __restrict__ oh, us* __restrict__ ol, int ldn,
    us* __restrict__ th, us* __restrict__ tl, int ldt,
    int R, int C)
{
    __shared__ float Ts[32][33];
    const int tx = threadIdx.x & 31, ty = threadIdx.x >> 5;
    const int c0 = blockIdx.x * 32, r0 = blockIdx.y * 32;
#pragma unroll
    for (int i = 0; i < 4; ++i) {
        const int r = ty + i * 8;
        const float v = in[(size_t)(r0 + r) * ldi + c0 + tx];
        Ts[r][tx] = v;
        __bf16 b  = (__bf16)v;
        __bf16 lo = (__bf16)(v - (float)b);
        const size_t o = (size_t)(r0 + r) * ldn + c0 + tx;
        oh[o] = __builtin_bit_cast(unsigned short, b);
        ol[o] = __builtin_bit_cast(unsigned short, lo);
    }
    __syncthreads();
#pragma unroll
    for (int i = 0; i < 4; ++i) {
        const int c = ty + i * 8;
        const float v = Ts[tx][c];
        __bf16 b  = (__bf16)v;
        __bf16 lo = (__bf16)(v - (float)b);
        const size_t o = (size_t)(c0 + c) * ldt + r0 + tx;
        th[o] = __builtin_bit_cast(unsigned short, b);
        tl[o] = __builtin_bit_cast(unsigned short, lo);
    }
}

// ===========================================================================
// Newton-Schulz helpers
// ===========================================================================
// max_r sum_c |S[r][c]|  (inf-norm >= spectral radius) -> atomicMax bits
__global__ __launch_bounds__(256) void rowabsmax_kernel(
    const float* __restrict__ S, int lds, unsigned int* __restrict__ out)
{
    __shared__ float wsum[4];
    const int r = blockIdx.x;
    float s = 0.f;
    for (int c = threadIdx.x; c < 512; c += 256) s += fabsf(S[(size_t)r * lds + c]);
#pragma unroll
    for (int o = 32; o > 0; o >>= 1) s += __shfl_down(s, o, 64);
    if ((threadIdx.x & 63) == 0) wsum[threadIdx.x >> 6] = s;
    __syncthreads();
    if (threadIdx.x == 0) {
        const float t = wsum[0] + wsum[1] + wsum[2] + wsum[3];
        atomicMax(out, __float_as_uint(t));  // positive floats: uint order == float order
    }
}

// X1 = 2a*I - a^2*S, a = 1/c  (first Newton iterate from X0 = a*I)
__global__ void initx1_kernel(const float* __restrict__ S, int lds,
                              const unsigned int* __restrict__ cmax,
                              float* __restrict__ X)
{
    const int idx = blockIdx.x * 256 + threadIdx.x;  // 512*512
    const float a = 1.f / __uint_as_float(*cmax);
    const int r = idx >> 9, c = idx & 511;
    X[idx] = 2.f * a * ((r == c) ? 1.f : 0.f) - a * a * S[(size_t)r * lds + c];
}

// ===========================================================================
// Fallback-path helpers (fp32 GJ inverse)
// ===========================================================================
__global__ __launch_bounds__(256) void inv64_kernel(
    const float* __restrict__ W, int ldw, int kb, float* __restrict__ Dinv)
{
    __shared__ float T[64][129];
    __shared__ float multcol[64];
    const int tid = threadIdx.x;

    for (int idx = tid; idx < 64 * 64; idx += 256) {
        const int r = idx >> 6, c = idx & 63;
        T[r][c]      = W[(size_t)(kb * 64 + r) * ldw + kb * 64 + c];
        T[r][64 + c] = (r == c) ? 1.f : 0.f;
    }
    __syncthreads();

    for (int p = 0; p < 64; ++p) {
        const float rp = 1.f / T[p][p];
        __syncthreads();
        if (tid < 128) T[p][tid] *= rp;
        if (tid >= 128 && tid < 192) multcol[tid - 128] = T[tid - 128][p];
        __syncthreads();
        for (int idx = tid; idx < 64 * 128; idx += 256) {
            const int r = idx >> 7, c = idx & 127;
            if (r != p) T[r][c] = fmaf(-multcol[r], T[p][c], T[r][c]);
        }
        __syncthreads();
    }

    for (int idx = tid; idx < 64 * 64; idx += 256) {
        const int r = idx >> 6, c = idx & 63;
        Dinv[idx] = T[r][64 + c];
    }
}

__global__ void init_eye_kernel(float* __restrict__ W)
{
    const int idx = blockIdx.x * 256 + threadIdx.x;
    if (idx < 512 * 512) {
        const int r = idx >> 9, c = idx & 511;
        W[(size_t)r * 1024 + 512 + c] = (r == c) ? 1.f : 0.f;
    }
}

__global__ void multcopy_kernel(const float* __restrict__ W, float* __restrict__ Mbuf, int kb)
{
    const int idx = blockIdx.x * 256 + threadIdx.x;
    if (idx < 512 * 64) {
        const int r = idx >> 6, c = idx & 63;
        const float v = W[(size_t)r * 1024 + kb * 64 + c];
        Mbuf[idx] = ((r >> 6) == kb) ? 0.f : v;
    }
}

static void run_gj_inverse(float* W, float* Mbuf, float* Dinv, hipStream_t stream)
{
    const dim3 blk(256);
    for (int kb = 0; kb < 8; ++kb) {
        inv64_kernel<<<dim3(1), blk, 0, stream>>>(W, 1024, kb, Dinv);
        gemm_f32<false><<<dim3(1024 / 128, 1), blk, 0, stream>>>(
            W + (size_t)kb * 64 * 1024, 1024, Dinv, 64,
            W + (size_t)kb * 64 * 1024, 1024, nullptr, 0, 64, 1024, 64, 1.f);
        multcopy_kernel<<<dim3((512 * 64) / 256), blk, 0, stream>>>(W, Mbuf, kb);
        gemm_f32<false><<<dim3(1024 / 128, 512 / 128), blk, 0, stream>>>(
            W, 1024, Mbuf, 64, W + (size_t)kb * 64 * 1024, 1024,
            W, 1024, 512, 1024, 64, -1.f);
    }
}

static void run_fp32_path(void* const* d_in, void* d_out, void* d_ws, hipStream_t stream)
{
    const float* state   = (const float*)d_in[0];
    const float* cov     = (const float*)d_in[1];
    const float* meas    = (const float*)d_in[2];
    const float* control = (const float*)d_in[3];
    const float* F       = (const float*)d_in[4];
    const float* Q       = (const float*)d_in[5];
    const float* Bc      = (const float*)d_in[6];
    const float* H       = (const float*)d_in[7];
    const float* R       = (const float*)d_in[8];

    float* out_state = (float*)d_out;
    float* out_cov   = out_state + (size_t)Dd * Bb;
    float* T1        = out_cov;

    float* ws    = (float*)d_ws;
    float* cov_p = ws;  ws += (size_t)Dd * Dd;
    float* HCP   = ws;  ws += (size_t)Mm * Dd;
    float* W     = ws;  ws += (size_t)Mm * 1024;
    float* Mbuf  = ws;  ws += (size_t)Mm * 64;
    float* Dinv  = ws;  ws += 64 * 64;
    float* Kg    = ws;  ws += (size_t)Dd * Mm;
    float* KHI   = ws;  ws += (size_t)Dd * Dd;

    const dim3 blk(256);
    gemm_f32<false><<<dim3(Dd / 128, Dd / 128), blk, 0, stream>>>(
        T1, Dd, F, Dd, cov, Dd, nullptr, 0, Dd, Dd, Dd, 1.f);
    gemm_f32<true><<<dim3(Dd / 128, Dd / 128), blk, 0, stream>>>(
        cov_p, Dd, T1, Dd, F, Dd, Q, Dd, Dd, Dd, Dd, 1.f);
    gemm_f32<false><<<dim3(Dd / 128, Mm / 128), blk, 0, stream>>>(
        HCP, Dd, H, Dd, cov_p, Dd, nullptr, 0, Mm, Dd, Dd, 1.f);
    gemm_f32<true><<<dim3(Mm / 128, Mm / 128), blk, 0, stream>>>(
        W, 1024, HCP, Dd, H, Dd, R, Mm, Mm, Mm, Dd, 1.f);
    init_eye_kernel<<<dim3((512 * 512) / 256), blk, 0, stream>>>(W);
    run_gj_inverse(W, Mbuf, Dinv, stream);
    float* Sinv = W + 512;
    gemm_f32<true><<<dim3(Mm / 128, Dd / 128), blk, 0, stream>>>(
        HCP, Mm, cov_p, Dd, H, Dd, nullptr, 0, Dd, Mm, Dd, 1.f);
    gemm_f32<false><<<dim3(Mm / 128, Dd / 128), blk, 0, stream>>>(
        Kg, Mm, HCP, Mm, Sinv, 1024, nullptr, 0, Dd, Mm, Mm, 1.f);
    gemm_f32<false><<<dim3(Dd / 128, Dd / 128), blk, 0, stream>>>(
        KHI, Dd, Kg, Mm, H, Dd, nullptr, 0, Dd, Dd, Mm, 1.f);
    gemm_f32<false><<<dim3(Dd / 128, Dd / 128), blk, 0, stream>>>(
        out_cov, Dd, KHI, Dd, cov_p, Dd, cov_p, Dd, Dd, Dd, Dd, -1.f);
    gemm_f32<false><<<dim3(Bb / 128, Dd / 128), blk, 0, stream>>>(
        out_state, Bb, F, Dd, state, Bb, nullptr, 0, Dd, Bb, Dd, 1.f);
    gemm_f32<false><<<dim3(Bb / 128, Dd / 128), blk, 0, stream>>>(
        out_state, Bb, Bc, Cc, control, Bb, out_state, Bb, Dd, Bb, Cc, 1.f);
    for (int b0 = 0; b0 < Bb; b0 += 2048) {
        float* innov_c = KHI;
        gemm_f32<false><<<dim3(2048 / 128, Mm / 128), blk, 0, stream>>>(
            innov_c, 2048, H, Dd, out_state + b0, Bb, meas + b0, Bb,
            Mm, 2048, Dd, -1.f);
        gemm_f32<false><<<dim3(2048 / 128, Dd / 128), blk, 0, stream>>>(
            out_state + b0, Bb, Kg, Mm, innov_c, 2048, out_state + b0, Bb,
            Dd, 2048, Mm, 1.f);
    }
}

extern "C" void kernel_launch(void* const* d_in, const int* in_sizes, int n_in,
                              void* d_out, int out_size, void* d_ws, size_t ws_size,
                              hipStream_t stream)
{
    if (ws_size < 68000000ull) { run_fp32_path(d_in, d_out, d_ws, stream); return; }

    const float* state   = (const float*)d_in[0];
    const float* cov     = (const float*)d_in[1];   // symmetric
    const float* meas    = (const float*)d_in[2];
    const float* control = (const float*)d_in[3];
    const float* F       = (const float*)d_in[4];
    const float* Q       = (const float*)d_in[5];
    const float* Bc      = (const float*)d_in[6];
    const float* H       = (const float*)d_in[7];
    const float* R       = (const float*)d_in[8];

    float* out_state = (float*)d_out;
    float* out_cov   = out_state + (size_t)Dd * Bb;   // holds T1 fp32 early

    // ---- workspace arena (same footprint as round 3; Newton aliases big/ar)
    size_t off = 0;
    auto alloc = [&](size_t bytes) {
        void* p = (char*)d_ws + off;
        off = (off + bytes + 255) & ~(size_t)255;
        return p;
    };
    float* covp  = (float*)alloc(4194304);
    float* W     = (float*)alloc(2097152);             // S lives in left half (ld 1024)
    float* Mbuf  = (float*)alloc(131072);              // cmax scalar lives here
    float* Dinv  = (float*)alloc(16384);
    float* Kgf   = (float*)alloc(2097152);
    float* mdbuf = (float*)alloc(2097152);
    float* big   = (float*)alloc(8388608);             // Newton X/Y/X2, later KH / innov
    us* FBc_h   = (us*)alloc(2621440);  us* FBc_l   = (us*)alloc(2621440);
    us* bt1_h   = (us*)alloc(2097152);  us* bt1_l   = (us*)alloc(2097152);
    us* bt2_h   = (us*)alloc(2097152);  us* bt2_l   = (us*)alloc(2097152);
    us* H_h     = (us*)alloc(1048576);  us* H_l     = (us*)alloc(1048576);
    us* HT_h    = (us*)alloc(1048576);  us* HT_l    = (us*)alloc(1048576);
    us* amh_h   = (us*)alloc(1048576);  us* amh_l   = (us*)alloc(1048576);
    us* SvT_h   = (us*)alloc(524288);   us* SvT_l   = (us*)alloc(524288);
    us* Kg_h    = (us*)alloc(1048576);  us* Kg_l    = (us*)alloc(1048576);
    us* KH_h    = (us*)alloc(2097152);  us* KH_l    = (us*)alloc(2097152);
    us* ar_h    = (us*)alloc(10485760); us* ar_l    = (us*)alloc(10485760);

    // Newton scratch (aliases; all dead elsewhere at inversion time)
    float* Xf  = big;                 // 512x512
    float* Yf  = big + 262144;
    float* X2f = big + 524288;
    us* S_h  = ar_h;            us* S_l  = ar_h + 262144;
    us* Xa_h = ar_h + 524288;   us* Xa_l = ar_h + 786432;
    us* Xt_h = ar_l;            us* Xt_l = ar_l + 262144;
    us* Yt_h = ar_l + 524288;   us* Yt_l = ar_l + 786432;
    unsigned int* cmax = (unsigned int*)Mbuf;

    const dim3 blk(256);
    auto cvt = [&](const float* in, int ldi, us* oh, us* ol, int ldo, int Rr, int Cn) {
        const int total4 = Rr * (Cn / 4);
        const int grid = min(4096, (total4 + 255) / 256);
        cvt_split_kernel<<<dim3(grid), blk, 0, stream>>>(in, ldi, oh, ol, ldo, Rr, Cn / 4);
    };
    auto cvtT = [&](const float* in, int ldi, us* oh, us* ol, int ldo, int Rr, int Cn) {
        cvt_split_t_kernel<<<dim3(Cn / 32, Rr / 32), blk, 0, stream>>>(in, ldi, oh, ol, ldo, Rr, Cn);
    };
    auto mm = [&](float* C, int ldc, const us* Ah, const us* Al, int lda,
                  const us* Bh, const us* Bl, int ldb, const float* ADD, int ldadd,
                  int M, int N, int K, float sign, float addscale) {
        if (ADD)
            gemm_bf16s<true><<<dim3(N / 128, M / 128), blk, 0, stream>>>(
                C, ldc, Ah, Al, lda, Bh, Bl, ldb, ADD, ldadd, M, N, K, sign, addscale);
        else
            gemm_bf16s<false><<<dim3(N / 128, M / 128), blk, 0, stream>>>(
                C, ldc, Ah, Al, lda, Bh, Bl, ldb, nullptr, 0, M, N, K, sign, 1.f);
    };

    // ---- operand conversions ----
    cvt(F, 1024, FBc_h, FBc_l, 1280, 1024, 1024);
    cvt(Bc, 256, FBc_h + 1024, FBc_l + 1024, 1280, 1024, 256);
    cvt(cov, 1024, bt1_h, bt1_l, 1024, 1024, 1024);        // cov symmetric -> Bt form
    cvt(H, 1024, H_h, H_l, 1024, 512, 1024);
    cvtT(H, 1024, HT_h, HT_l, 512, 512, 1024);

    // ---- covariance chain ----
    mm(out_cov, 1024, FBc_h, FBc_l, 1280, bt1_h, bt1_l, 1024, nullptr, 0, 1024, 1024, 1024, 1.f, 1.f);
    cvt(out_cov, 1024, bt2_h, bt2_l, 1024, 1024, 1024);    // T1_hl
    mm(covp, 1024, bt2_h, bt2_l, 1024, FBc_h, FBc_l, 1280, Q, 1024, 1024, 1024, 1024, 1.f, 1.f);
    cvt(covp, 1024, bt1_h, bt1_l, 1024, 1024, 1024);       // covp A-form
    cvtT(covp, 1024, bt2_h, bt2_l, 1024, 1024, 1024);      // covp^T Bt-form
    mm(mdbuf, 1024, H_h, H_l, 1024, bt2_h, bt2_l, 1024, nullptr, 0, 512, 1024, 1024, 1.f, 1.f);
    cvt(mdbuf, 1024, amh_h, amh_l, 1024, 512, 1024);       // HC_hl
    mm(W, 1024, amh_h, amh_l, 1024, H_h, H_l, 1024, R, 512, 512, 512, 1024, 1.f, 1.f);  // S

    // ---- Newton-Schulz inverse of S (512x512, in W left half ld 1024) ----
    hipMemsetAsync(cmax, 0, 4, stream);
    rowabsmax_kernel<<<dim3(512), blk, 0, stream>>>(W, 1024, cmax);
    initx1_kernel<<<dim3(1024), blk, 0, stream>>>(W, 1024, cmax, Xf);
    cvt(W, 1024, S_h, S_l, 512, 512, 512);                 // S A-form
    for (int it = 0; it < 7; ++it) {
        cvt_split_both_kernel<<<dim3(16, 16), blk, 0, stream>>>(
            Xf, 512, Xa_h, Xa_l, 512, Xt_h, Xt_l, 512, 512, 512);
        // Y = S @ X
        mm(Yf, 512, S_h, S_l, 512, Xt_h, Xt_l, 512, nullptr, 0, 512, 512, 512, 1.f, 1.f);
        cvtT(Yf, 512, Yt_h, Yt_l, 512, 512, 512);
        // X' = 2X - X @ Y
        mm(X2f, 512, Xa_h, Xa_l, 512, Yt_h, Yt_l, 512, Xf, 512, 512, 512, 512, -1.f, 2.f);
        float* t = Xf; Xf = X2f; X2f = t;
    }
    cvtT(Xf, 512, SvT_h, SvT_l, 512, 512, 512);            // Sinv^T Bt-form

    // ---- gain + covariance update ----
    mm(mdbuf, 512, bt1_h, bt1_l, 1024, H_h, H_l, 1024, nullptr, 0, 1024, 512, 1024, 1.f, 1.f);  // PHT
    cvt(mdbuf, 512, amh_h, amh_l, 512, 1024, 512);
    mm(Kgf, 512, amh_h, amh_l, 512, SvT_h, SvT_l, 512, nullptr, 0, 1024, 512, 512, 1.f, 1.f);   // Kg
    cvt(Kgf, 512, Kg_h, Kg_l, 512, 1024, 512);
    mm(big, 1024, Kg_h, Kg_l, 512, HT_h, HT_l, 512, nullptr, 0, 1024, 1024, 512, 1.f, 1.f);     // KH
    cvt(big, 1024, KH_h, KH_l, 1024, 1024, 1024);
    mm(out_cov, 1024, KH_h, KH_l, 1024, bt2_h, bt2_l, 1024, covp, 1024, 1024, 1024, 1024, -1.f, 1.f);

    // ---- state chain, 2 chunks of 4096 columns ----
    for (int b0 = 0; b0 < Bb; b0 += 4096) {
        cvtT(state + b0, 8192, ar_h, ar_l, 1280, 1024, 4096);
        cvtT(control + b0, 8192, ar_h + 1024, ar_l + 1024, 1280, 256, 4096);
        mm(out_state + b0, 8192, FBc_h, FBc_l, 1280, ar_h, ar_l, 1280,
           nullptr, 0, 1024, 4096, 1280, 1.f, 1.f);
        cvtT(out_state + b0, 8192, ar_h, ar_l, 1024, 1024, 4096);
        mm(big, 4096, H_h, H_l, 1024, ar_h, ar_l, 1024, meas + b0, 8192,
           512, 4096, 1024, -1.f, 1.f);
        cvtT(big, 4096, ar_h, ar_l, 512, 512, 4096);
        mm(out_state + b0, 8192, Kg_h, Kg_l, 512, ar_h, ar_l, 512,
           out_state + b0, 8192, 1024, 4096, 512, 1.f, 1.f);
    }
}

// Round 5
// 826.607 us; speedup vs baseline: 5.0453x; 2.4548x over previous
//
#include <hip/hip_runtime.h>

// Kalman filter fused step. D=1024, M=512, C=256, B=8192, fp32 in/out.
// Fast path: split-bf16 (hi+lo) MFMA GEMMs with global_load_lds staging
// (XOR-swizzled), fused split/transpose epilogues, Newton-Schulz inverse.
// Fallback (ws too small): fp32 vector-ALU path with blocked GJ inverse.

static constexpr int Dd = 1024;
static constexpr int Mm = 512;
static constexpr int Cc = 256;
static constexpr int Bb = 8192;

typedef __bf16 bf16x8 __attribute__((ext_vector_type(8)));
typedef float f32x4 __attribute__((ext_vector_type(4)));
typedef unsigned short us;

// ---------------------------------------------------------------------------
// async global->LDS, 16 bytes per lane (literal size required)
// ---------------------------------------------------------------------------
__device__ __forceinline__ void gl16(const void* g, void* l)
{
    __builtin_amdgcn_global_load_lds(
        (const __attribute__((address_space(1))) void*)g,
        (__attribute__((address_space(3))) void*)l, 16, 0, 0);
}

__device__ __forceinline__ us bf16_hi(float v)
{
    return __builtin_bit_cast(us, (__bf16)v);
}
__device__ __forceinline__ us bf16_lo(float v)
{
    const __bf16 b = (__bf16)v;
    return __builtin_bit_cast(us, (__bf16)(v - (float)b));
}

// ===========================================================================
// Split-bf16 MFMA GEMM with fused epilogue.
//   C = addscale*ADD + sign * (A @ Bt^T)
//   A:[M,K] hi/lo (lda shorts); Bt:[N,K] hi/lo (ldb shorts). M,N%128, K%64.
// MODE bit0: write fp32 Cp (ldc). bit1: write split oh/ol [M,N] (ldo).
// bit2: write transposed split th/tl [N,M] (ldt).
// Staging: global_load_lds w=16 into linear LDS; bank-conflict-free via
// XOR swizzle (slot ^= row&7) applied to SOURCE address and ds_read only.
// ===========================================================================
template <int MODE, bool HAS_ADD>
__global__ __launch_bounds__(256) void gemm_bf16s(
    float* __restrict__ Cp, int ldc,
    us* __restrict__ oh, us* __restrict__ ol, int ldo,
    us* __restrict__ th, us* __restrict__ tl, int ldt,
    const us* __restrict__ Ahi, const us* __restrict__ Alo, int lda,
    const us* __restrict__ Bhi, const us* __restrict__ Blo, int ldb,
    const float* __restrict__ ADDp, int ldadd,
    int M, int N, int K, float sign, float addscale)
{
    __shared__ __align__(16) us lds[4][128][64];   // Ahi,Alo,Bhi,Blo tiles

    const int tid  = threadIdx.x;
    const int wave = tid >> 6, lane = tid & 63;
    const int l15  = lane & 15, lk = lane >> 4;
    const int wr   = (wave >> 1) * 64, wc = (wave & 1) * 64;
    const int row0 = blockIdx.y * 128, col0 = blockIdx.x * 128;

    // per-thread staging geometry (constant across K)
    int offA[4], offB[4];
#pragma unroll
    for (int j = 0; j < 4; ++j) {
        const int id  = j * 256 + tid;     // 0..1023 16B-slots
        const int r   = id >> 3;           // tile row 0..127
        const int c16 = id & 7;            // 16B slot within 128B row
        const int csw = c16 ^ (r & 7);     // pre-swizzled source slot
        offA[j] = (row0 + r) * lda * 2 + csw * 16;
        offB[j] = (col0 + r) * ldb * 2 + csw * 16;
    }
    const char* pAh = (const char*)Ahi;
    const char* pAl = (const char*)Alo;
    const char* pBh = (const char*)Bhi;
    const char* pBl = (const char*)Blo;
    char* dA0 = (char*)&lds[0][0][0];
    char* dA1 = (char*)&lds[1][0][0];
    char* dB0 = (char*)&lds[2][0][0];
    char* dB1 = (char*)&lds[3][0][0];

    const int sl0 = (0 * 4 + lk) ^ (l15 & 7);   // ks=0 read slot
    const int sl1 = (1 * 4 + lk) ^ (l15 & 7);   // ks=1 read slot

    f32x4 acc[4][4] = {};

    for (int k0 = 0; k0 < K; k0 += 64) {
        const int k2 = k0 * 2;
#pragma unroll
        for (int j = 0; j < 4; ++j) {
            const int d = (j * 256 + tid) * 16;
            gl16(pAh + offA[j] + k2, dA0 + d);
            gl16(pAl + offA[j] + k2, dA1 + d);
            gl16(pBh + offB[j] + k2, dB0 + d);
            gl16(pBl + offB[j] + k2, dB1 + d);
        }
        __syncthreads();   // compiler emits vmcnt(0) drain before barrier

#pragma unroll
        for (int ks = 0; ks < 2; ++ks) {
            const int sl = ks ? sl1 : sl0;
            bf16x8 ah[4], al[4], bh[4], bl[4];
#pragma unroll
            for (int mi = 0; mi < 4; ++mi) {
                ah[mi] = *reinterpret_cast<const bf16x8*>(&lds[0][wr + mi * 16 + l15][sl * 8]);
                al[mi] = *reinterpret_cast<const bf16x8*>(&lds[1][wr + mi * 16 + l15][sl * 8]);
                bh[mi] = *reinterpret_cast<const bf16x8*>(&lds[2][wc + mi * 16 + l15][sl * 8]);
                bl[mi] = *reinterpret_cast<const bf16x8*>(&lds[3][wc + mi * 16 + l15][sl * 8]);
            }
#pragma unroll
            for (int mi = 0; mi < 4; ++mi)
#pragma unroll
                for (int nj = 0; nj < 4; ++nj) {
                    acc[mi][nj] = __builtin_amdgcn_mfma_f32_16x16x32_bf16(ah[mi], bh[nj], acc[mi][nj], 0, 0, 0);
                    acc[mi][nj] = __builtin_amdgcn_mfma_f32_16x16x32_bf16(ah[mi], bl[nj], acc[mi][nj], 0, 0, 0);
                    acc[mi][nj] = __builtin_amdgcn_mfma_f32_16x16x32_bf16(al[mi], bh[nj], acc[mi][nj], 0, 0, 0);
                }
        }
        __syncthreads();
    }

#pragma unroll
    for (int mi = 0; mi < 4; ++mi)
#pragma unroll
        for (int nj = 0; nj < 4; ++nj)
#pragma unroll
            for (int rr = 0; rr < 4; ++rr) {
                const int gr = row0 + wr + mi * 16 + lk * 4 + rr;
                const int gc = col0 + wc + nj * 16 + l15;
                float v = sign * acc[mi][nj][rr];
                if (HAS_ADD) v = fmaf(addscale, ADDp[(size_t)gr * ldadd + gc], v);
                if constexpr (MODE & 1)
                    Cp[(size_t)gr * ldc + gc] = v;
                if constexpr (MODE & 2) {
                    oh[(size_t)gr * ldo + gc] = bf16_hi(v);
                    ol[(size_t)gr * ldo + gc] = bf16_lo(v);
                }
                if constexpr (MODE & 4) {
                    th[(size_t)gc * ldt + gr] = bf16_hi(v);
                    tl[(size_t)gc * ldt + gr] = bf16_lo(v);
                }
            }
}

// ===========================================================================
// fp32 [R,C] (ldi) -> bf16 hi/lo [R,C] (ldo). C%4==0.
// ===========================================================================
__global__ void cvt_split_kernel(const float* __restrict__ in, int ldi,
                                 us* __restrict__ oh, us* __restrict__ ol, int ldo,
                                 int R, int Cq)
{
    const int total = R * Cq;
    for (int idx = blockIdx.x * blockDim.x + threadIdx.x; idx < total;
         idx += gridDim.x * blockDim.x) {
        const int r  = idx / Cq;
        const int c  = (idx - r * Cq) * 4;
        const float4 v = *reinterpret_cast<const float4*>(in + (size_t)r * ldi + c);
        const float vv[4] = {v.x, v.y, v.z, v.w};
        ushort4 h, l;
        unsigned short hs[4], ls[4];
#pragma unroll
        for (int j = 0; j < 4; ++j) { hs[j] = bf16_hi(vv[j]); ls[j] = bf16_lo(vv[j]); }
        h.x = hs[0]; h.y = hs[1]; h.z = hs[2]; h.w = hs[3];
        l.x = ls[0]; l.y = ls[1]; l.z = ls[2]; l.w = ls[3];
        *reinterpret_cast<ushort4*>(oh + (size_t)r * ldo + c) = h;
        *reinterpret_cast<ushort4*>(ol + (size_t)r * ldo + c) = l;
    }
}

// ===========================================================================
// fp32 [R,C] (ldi) -> transposed bf16 hi/lo [C,R] (ldo). R,C %32==0.
// ===========================================================================
__global__ __launch_bounds__(256) void cvt_split_t_kernel(
    const float* __restrict__ in, int ldi,
    us* __restrict__ oh, us* __restrict__ ol, int ldo,
    int R, int C)
{
    __shared__ float Ts[32][33];
    const int tx = threadIdx.x & 31, ty = threadIdx.x >> 5;
    const int c0 = blockIdx.x * 32, r0 = blockIdx.y * 32;
#pragma unroll
    for (int i = 0; i < 4; ++i) {
        const int r = ty + i * 8;
        Ts[r][tx] = in[(size_t)(r0 + r) * ldi + c0 + tx];
    }
    __syncthreads();
#pragma unroll
    for (int i = 0; i < 4; ++i) {
        const int c = ty + i * 8;
        const float v = Ts[tx][c];
        const size_t o = (size_t)(c0 + c) * ldo + r0 + tx;
        oh[o] = bf16_hi(v);
        ol[o] = bf16_lo(v);
    }
}

// ===========================================================================
// fp32 [R,C] -> BOTH normal hi/lo (ldn) and transposed hi/lo (ldt)
// ===========================================================================
__global__ __launch_bounds__(256) void cvt_split_both_kernel(
    const float* __restrict__ in, int ldi,
    us* __restrict__ oh, us* __restrict__ ol, int ldn,
    us* __restrict__ th, us* __restrict__ tl, int ldt,
    int R, int C)
{
    __shared__ float Ts[32][33];
    const int tx = threadIdx.x & 31, ty = threadIdx.x >> 5;
    const int c0 = blockIdx.x * 32, r0 = blockIdx.y * 32;
#pragma unroll
    for (int i = 0; i < 4; ++i) {
        const int r = ty + i * 8;
        const float v = in[(size_t)(r0 + r) * ldi + c0 + tx];
        Ts[r][tx] = v;
        const size_t o = (size_t)(r0 + r) * ldn + c0 + tx;
        oh[o] = bf16_hi(v);
        ol[o] = bf16_lo(v);
    }
    __syncthreads();
#pragma unroll
    for (int i = 0; i < 4; ++i) {
        const int c = ty + i * 8;
        const float v = Ts[tx][c];
        const size_t o = (size_t)(c0 + c) * ldt + r0 + tx;
        th[o] = bf16_hi(v);
        tl[o] = bf16_lo(v);
    }
}

// ===========================================================================
// Newton-Schulz helpers
// ===========================================================================
__global__ __launch_bounds__(256) void rowabsmax_kernel(
    const float* __restrict__ S, int lds_, unsigned int* __restrict__ out)
{
    __shared__ float wsum[4];
    const int r = blockIdx.x;
    float s = 0.f;
    for (int c = threadIdx.x; c < 512; c += 256) s += fabsf(S[(size_t)r * lds_ + c]);
#pragma unroll
    for (int o = 32; o > 0; o >>= 1) s += __shfl_down(s, o, 64);
    if ((threadIdx.x & 63) == 0) wsum[threadIdx.x >> 6] = s;
    __syncthreads();
    if (threadIdx.x == 0) {
        const float t = wsum[0] + wsum[1] + wsum[2] + wsum[3];
        atomicMax(out, __float_as_uint(t));
    }
}

__global__ void initx1_kernel(const float* __restrict__ S, int lds_,
                              const unsigned int* __restrict__ cmax,
                              float* __restrict__ X)
{
    const int idx = blockIdx.x * 256 + threadIdx.x;  // 512*512
    const float a = 1.f / __uint_as_float(*cmax);
    const int r = idx >> 9, c = idx & 511;
    X[idx] = 2.f * a * ((r == c) ? 1.f : 0.f) - a * a * S[(size_t)r * lds_ + c];
}

// ===========================================================================
// fp32 fallback path (unchanged from round 2/3; only used if ws tiny)
// ===========================================================================
template <bool TRANSB>
__global__ __launch_bounds__(256) void gemm_f32(
    float* __restrict__ Cp, int ldc,
    const float* __restrict__ Ap, int lda,
    const float* __restrict__ Bp, int ldb,
    const float* __restrict__ ADDp, int ldadd,
    int M, int N, int K, float sign)
{
    __shared__ float As[16][132];
    __shared__ float Bs[16][132];
    const int tid  = threadIdx.x;
    const int row0 = blockIdx.y * 128;
    const int col0 = blockIdx.x * 128;
    const int tr   = tid >> 4;
    const int tc   = tid & 15;
    float acc[8][8];
#pragma unroll
    for (int i = 0; i < 8; ++i)
#pragma unroll
        for (int j = 0; j < 8; ++j) acc[i][j] = 0.f;

    for (int k0 = 0; k0 < K; k0 += 16) {
#pragma unroll
        for (int l = 0; l < 2; ++l) {
            const int f = tid + l * 256;
            const int r = f >> 2;
            const int kq = (f & 3) << 2;
            const int grow = row0 + r;
            float4 v = make_float4(0.f, 0.f, 0.f, 0.f);
            if (grow < M)
                v = *reinterpret_cast<const float4*>(Ap + (size_t)grow * lda + k0 + kq);
            As[kq + 0][r] = v.x; As[kq + 1][r] = v.y;
            As[kq + 2][r] = v.z; As[kq + 3][r] = v.w;
        }
        if (!TRANSB) {
#pragma unroll
            for (int l = 0; l < 2; ++l) {
                const int f = tid + l * 256;
                const int kk = f >> 5;
                const int cq = (f & 31) << 2;
                const int gcol = col0 + cq;
                float4 v = make_float4(0.f, 0.f, 0.f, 0.f);
                if (gcol + 3 < N)
                    v = *reinterpret_cast<const float4*>(Bp + (size_t)(k0 + kk) * ldb + gcol);
                *reinterpret_cast<float4*>(&Bs[kk][cq]) = v;
            }
        } else {
#pragma unroll
            for (int l = 0; l < 2; ++l) {
                const int f = tid + l * 256;
                const int n = f >> 2;
                const int kq = (f & 3) << 2;
                const int gcol = col0 + n;
                float4 v = make_float4(0.f, 0.f, 0.f, 0.f);
                if (gcol < N)
                    v = *reinterpret_cast<const float4*>(Bp + (size_t)gcol * ldb + k0 + kq);
                Bs[kq + 0][n] = v.x; Bs[kq + 1][n] = v.y;
                Bs[kq + 2][n] = v.z; Bs[kq + 3][n] = v.w;
            }
        }
        __syncthreads();
#pragma unroll
        for (int kk = 0; kk < 16; ++kk) {
            const float4 a0 = *reinterpret_cast<const float4*>(&As[kk][tr * 8]);
            const float4 a1 = *reinterpret_cast<const float4*>(&As[kk][tr * 8 + 4]);
            const float4 b0 = *reinterpret_cast<const float4*>(&Bs[kk][tc * 8]);
            const float4 b1 = *reinterpret_cast<const float4*>(&Bs[kk][tc * 8 + 4]);
            const float a_frag[8] = {a0.x, a0.y, a0.z, a0.w, a1.x, a1.y, a1.z, a1.w};
            const float b_frag[8] = {b0.x, b0.y, b0.z, b0.w, b1.x, b1.y, b1.z, b1.w};
#pragma unroll
            for (int i = 0; i < 8; ++i)
#pragma unroll
                for (int j = 0; j < 8; ++j)
                    acc[i][j] = fmaf(a_frag[i], b_frag[j], acc[i][j]);
        }
        __syncthreads();
    }
#pragma unroll
    for (int i = 0; i < 8; ++i) {
        const int grow = row0 + tr * 8 + i;
        if (grow >= M) continue;
        const int gcol = col0 + tc * 8;
#pragma unroll
        for (int j = 0; j < 8; ++j) {
            const int gc = gcol + j;
            if (gc < N) {
                const float add = ADDp ? ADDp[(size_t)grow * ldadd + gc] : 0.f;
                Cp[(size_t)grow * ldc + gc] = fmaf(sign, acc[i][j], add);
            }
        }
    }
}

__global__ __launch_bounds__(256) void inv64_kernel(
    const float* __restrict__ W, int ldw, int kb, float* __restrict__ Dinv)
{
    __shared__ float T[64][129];
    __shared__ float multcol[64];
    const int tid = threadIdx.x;
    for (int idx = tid; idx < 64 * 64; idx += 256) {
        const int r = idx >> 6, c = idx & 63;
        T[r][c]      = W[(size_t)(kb * 64 + r) * ldw + kb * 64 + c];
        T[r][64 + c] = (r == c) ? 1.f : 0.f;
    }
    __syncthreads();
    for (int p = 0; p < 64; ++p) {
        const float rp = 1.f / T[p][p];
        __syncthreads();
        if (tid < 128) T[p][tid] *= rp;
        if (tid >= 128 && tid < 192) multcol[tid - 128] = T[tid - 128][p];
        __syncthreads();
        for (int idx = tid; idx < 64 * 128; idx += 256) {
            const int r = idx >> 7, c = idx & 127;
            if (r != p) T[r][c] = fmaf(-multcol[r], T[p][c], T[r][c]);
        }
        __syncthreads();
    }
    for (int idx = tid; idx < 64 * 64; idx += 256) {
        const int r = idx >> 6, c = idx & 63;
        Dinv[idx] = T[r][64 + c];
    }
}

__global__ void init_eye_kernel(float* __restrict__ W)
{
    const int idx = blockIdx.x * 256 + threadIdx.x;
    if (idx < 512 * 512) {
        const int r = idx >> 9, c = idx & 511;
        W[(size_t)r * 1024 + 512 + c] = (r == c) ? 1.f : 0.f;
    }
}

__global__ void multcopy_kernel(const float* __restrict__ W, float* __restrict__ Mbuf, int kb)
{
    const int idx = blockIdx.x * 256 + threadIdx.x;
    if (idx < 512 * 64) {
        const int r = idx >> 6, c = idx & 63;
        const float v = W[(size_t)r * 1024 + kb * 64 + c];
        Mbuf[idx] = ((r >> 6) == kb) ? 0.f : v;
    }
}

static void run_fp32_path(void* const* d_in, void* d_out, void* d_ws, hipStream_t stream)
{
    const float* state   = (const float*)d_in[0];
    const float* cov     = (const float*)d_in[1];
    const float* meas    = (const float*)d_in[2];
    const float* control = (const float*)d_in[3];
    const float* F       = (const float*)d_in[4];
    const float* Q       = (const float*)d_in[5];
    const float* Bc      = (const float*)d_in[6];
    const float* H       = (const float*)d_in[7];
    const float* R       = (const float*)d_in[8];

    float* out_state = (float*)d_out;
    float* out_cov   = out_state + (size_t)Dd * Bb;
    float* T1        = out_cov;

    float* ws    = (float*)d_ws;
    float* cov_p = ws;  ws += (size_t)Dd * Dd;
    float* HCP   = ws;  ws += (size_t)Mm * Dd;
    float* W     = ws;  ws += (size_t)Mm * 1024;
    float* Mbuf  = ws;  ws += (size_t)Mm * 64;
    float* Dinv  = ws;  ws += 64 * 64;
    float* Kg    = ws;  ws += (size_t)Dd * Mm;
    float* KHI   = ws;  ws += (size_t)Dd * Dd;

    const dim3 blk(256);
    gemm_f32<false><<<dim3(Dd / 128, Dd / 128), blk, 0, stream>>>(
        T1, Dd, F, Dd, cov, Dd, nullptr, 0, Dd, Dd, Dd, 1.f);
    gemm_f32<true><<<dim3(Dd / 128, Dd / 128), blk, 0, stream>>>(
        cov_p, Dd, T1, Dd, F, Dd, Q, Dd, Dd, Dd, Dd, 1.f);
    gemm_f32<false><<<dim3(Dd / 128, Mm / 128), blk, 0, stream>>>(
        HCP, Dd, H, Dd, cov_p, Dd, nullptr, 0, Mm, Dd, Dd, 1.f);
    gemm_f32<true><<<dim3(Mm / 128, Mm / 128), blk, 0, stream>>>(
        W, 1024, HCP, Dd, H, Dd, R, Mm, Mm, Mm, Dd, 1.f);
    init_eye_kernel<<<dim3((512 * 512) / 256), blk, 0, stream>>>(W);
    for (int kb = 0; kb < 8; ++kb) {
        inv64_kernel<<<dim3(1), blk, 0, stream>>>(W, 1024, kb, Dinv);
        gemm_f32<false><<<dim3(1024 / 128, 1), blk, 0, stream>>>(
            W + (size_t)kb * 64 * 1024, 1024, Dinv, 64,
            W + (size_t)kb * 64 * 1024, 1024, nullptr, 0, 64, 1024, 64, 1.f);
        multcopy_kernel<<<dim3((512 * 64) / 256), blk, 0, stream>>>(W, Mbuf, kb);
        gemm_f32<false><<<dim3(1024 / 128, 512 / 128), blk, 0, stream>>>(
            W, 1024, Mbuf, 64, W + (size_t)kb * 64 * 1024, 1024,
            W, 1024, 512, 1024, 64, -1.f);
    }
    float* Sinv = W + 512;
    gemm_f32<true><<<dim3(Mm / 128, Dd / 128), blk, 0, stream>>>(
        HCP, Mm, cov_p, Dd, H, Dd, nullptr, 0, Dd, Mm, Dd, 1.f);
    gemm_f32<false><<<dim3(Mm / 128, Dd / 128), blk, 0, stream>>>(
        Kg, Mm, HCP, Mm, Sinv, 1024, nullptr, 0, Dd, Mm, Mm, 1.f);
    gemm_f32<false><<<dim3(Dd / 128, Dd / 128), blk, 0, stream>>>(
        KHI, Dd, Kg, Mm, H, Dd, nullptr, 0, Dd, Dd, Mm, 1.f);
    gemm_f32<false><<<dim3(Dd / 128, Dd / 128), blk, 0, stream>>>(
        out_cov, Dd, KHI, Dd, cov_p, Dd, cov_p, Dd, Dd, Dd, Dd, -1.f);
    gemm_f32<false><<<dim3(Bb / 128, Dd / 128), blk, 0, stream>>>(
        out_state, Bb, F, Dd, state, Bb, nullptr, 0, Dd, Bb, Dd, 1.f);
    gemm_f32<false><<<dim3(Bb / 128, Dd / 128), blk, 0, stream>>>(
        out_state, Bb, Bc, Cc, control, Bb, out_state, Bb, Dd, Bb, Cc, 1.f);
    for (int b0 = 0; b0 < Bb; b0 += 2048) {
        float* innov_c = KHI;
        gemm_f32<false><<<dim3(2048 / 128, Mm / 128), blk, 0, stream>>>(
            innov_c, 2048, H, Dd, out_state + b0, Bb, meas + b0, Bb,
            Mm, 2048, Dd, -1.f);
        gemm_f32<false><<<dim3(2048 / 128, Dd / 128), blk, 0, stream>>>(
            out_state + b0, Bb, Kg, Mm, innov_c, 2048, out_state + b0, Bb,
            Dd, 2048, Mm, 1.f);
    }
}

// ===========================================================================
// launch
// ===========================================================================
extern "C" void kernel_launch(void* const* d_in, const int* in_sizes, int n_in,
                              void* d_out, int out_size, void* d_ws, size_t ws_size,
                              hipStream_t stream)
{
    if (ws_size < 46000000ull) { run_fp32_path(d_in, d_out, d_ws, stream); return; }

    const float* state   = (const float*)d_in[0];
    const float* cov     = (const float*)d_in[1];   // symmetric
    const float* meas    = (const float*)d_in[2];
    const float* control = (const float*)d_in[3];
    const float* F       = (const float*)d_in[4];
    const float* Q       = (const float*)d_in[5];
    const float* Bc      = (const float*)d_in[6];
    const float* H       = (const float*)d_in[7];
    const float* R       = (const float*)d_in[8];

    float* out_state = (float*)d_out;
    float* out_cov   = out_state + (size_t)Dd * Bb;

    const int NC = (ws_size >= 78000000ull) ? 8192 : 4096;   // state-chain chunk

    // ---- arena ----
    size_t off = 0;
    auto alloc = [&](size_t bytes) {
        void* p = (char*)d_ws + off;
        off = (off + bytes + 255) & ~(size_t)255;
        return p;
    };
    // persistent (live through cov + state chains)
    us* FBc_h = (us*)alloc(2621440);  us* FBc_l = (us*)alloc(2621440);  // [1024,1280]
    us* H_h   = (us*)alloc(1048576);  us* H_l   = (us*)alloc(1048576);  // [512,1024]
    us* HT_h  = (us*)alloc(1048576);  us* HT_l  = (us*)alloc(1048576);  // [1024,512]
    us* Kg_h  = (us*)alloc(1048576);  us* Kg_l  = (us*)alloc(1048576);  // [1024,512]
    const size_t scr0 = off;   // scratch region start (cov-era, later overlaid)

    // cov-era scratch
    float* covp = (float*)alloc(4194304);                               // [1024,1024] fp32
    us* cA_h  = (us*)alloc(2097152);  us* cA_l  = (us*)alloc(2097152);  // cov, then covp A-form
    us* cT_h  = (us*)alloc(2097152);  us* cT_l  = (us*)alloc(2097152);  // covp T-form
    float* Sf = (float*)alloc(1048576);                                 // [512,512] fp32
    us* S_h   = (us*)alloc(524288);   us* S_l   = (us*)alloc(524288);
    us* t1_h  = (us*)alloc(2097152);  us* t1_l  = (us*)alloc(2097152);  // T1 A-form
    us* amh_h = (us*)alloc(1048576);  us* amh_l = (us*)alloc(1048576);  // HC then PHT
    us* KH_h  = (us*)alloc(2097152);  us* KH_l  = (us*)alloc(2097152);  // [1024,1024]
    unsigned int* cmax = (unsigned int*)alloc(256);
    // Newton ping-pong
    float* Xf   = (float*)alloc(1048576);
    us* Xa_h = (us*)alloc(524288);  us* Xa_l = (us*)alloc(524288);
    us* Xt_h = (us*)alloc(524288);  us* Xt_l = (us*)alloc(524288);
    float* X2f  = (float*)alloc(1048576);
    us* X2a_h = (us*)alloc(524288); us* X2a_l = (us*)alloc(524288);
    us* X2t_h = (us*)alloc(524288); us* X2t_l = (us*)alloc(524288);
    us* Yt_h  = (us*)alloc(524288); us* Yt_l  = (us*)alloc(524288);

    // state-era scratch (OVERLAYS cov-era region; used only after cov chain)
    size_t soff = scr0;
    auto salloc = [&](size_t bytes) {
        void* p = (char*)d_ws + soff;
        soff = (soff + bytes + 255) & ~(size_t)255;
        return p;
    };
    us* ar_h  = (us*)salloc((size_t)NC * 1280 * 2);
    us* ar_l  = (us*)salloc((size_t)NC * 1280 * 2);
    us* ivT_h = (us*)salloc((size_t)NC * 512 * 2);
    us* ivT_l = (us*)salloc((size_t)NC * 512 * 2);

    const dim3 blk(256);
    auto cvt = [&](const float* in, int ldi, us* oh, us* ol, int ldo, int Rr, int Cn) {
        const int total4 = Rr * (Cn / 4);
        const int grid = min(4096, (total4 + 255) / 256);
        cvt_split_kernel<<<dim3(grid), blk, 0, stream>>>(in, ldi, oh, ol, ldo, Rr, Cn / 4);
    };
    auto cvtT = [&](const float* in, int ldi, us* oh, us* ol, int ldo, int Rr, int Cn) {
        cvt_split_t_kernel<<<dim3(Cn / 32, Rr / 32), blk, 0, stream>>>(in, ldi, oh, ol, ldo, Rr, Cn);
    };

#define MM(MODE, Cp, ldc, oh, ol, ldo, th, tl, ldt, Ah, Al, lda, Bh, Bl, ldb, ADD, ldadd, M_, N_, K_, sg, as_)      \
    do {                                                                                                            \
        if ((ADD) != nullptr)                                                                                       \
            gemm_bf16s<MODE, true><<<dim3((N_) / 128, (M_) / 128), blk, 0, stream>>>(                               \
                Cp, ldc, oh, ol, ldo, th, tl, ldt, Ah, Al, lda, Bh, Bl, ldb, ADD, ldadd, M_, N_, K_, sg, as_);      \
        else                                                                                                        \
            gemm_bf16s<MODE, false><<<dim3((N_) / 128, (M_) / 128), blk, 0, stream>>>(                              \
                Cp, ldc, oh, ol, ldo, th, tl, ldt, Ah, Al, lda, Bh, Bl, ldb, nullptr, 0, M_, N_, K_, sg, as_);      \
    } while (0)

    // ---- input conversions ----
    cvt(F, 1024, FBc_h, FBc_l, 1280, 1024, 1024);
    cvt(Bc, 256, FBc_h + 1024, FBc_l + 1024, 1280, 1024, 256);
    cvt(cov, 1024, cA_h, cA_l, 1024, 1024, 1024);    // cov (symmetric) Bt-form
    cvt(H, 1024, H_h, H_l, 1024, 512, 1024);
    cvtT(H, 1024, HT_h, HT_l, 512, 512, 1024);

    // ---- covariance chain ----
    // T1 = F @ cov -> split only
    MM(2, (float*)nullptr, 0, t1_h, t1_l, 1024, (us*)nullptr, (us*)nullptr, 0,
       FBc_h, FBc_l, 1280, cA_h, cA_l, 1024, (const float*)nullptr, 0, 1024, 1024, 1024, 1.f, 1.f);
    // covp = T1 @ F^T + Q -> fp32 + A-form + T-form
    MM(7, covp, 1024, cA_h, cA_l, 1024, cT_h, cT_l, 1024,
       t1_h, t1_l, 1024, FBc_h, FBc_l, 1280, Q, 1024, 1024, 1024, 1024, 1.f, 1.f);
    // HC = H @ covp -> split
    MM(2, (float*)nullptr, 0, amh_h, amh_l, 1024, (us*)nullptr, (us*)nullptr, 0,
       H_h, H_l, 1024, cT_h, cT_l, 1024, (const float*)nullptr, 0, 512, 1024, 1024, 1.f, 1.f);
    // S = HC @ H^T + R -> fp32 + split
    MM(3, Sf, 512, S_h, S_l, 512, (us*)nullptr, (us*)nullptr, 0,
       amh_h, amh_l, 1024, H_h, H_l, 1024, R, 512, 512, 512, 1024, 1.f, 1.f);

    // ---- Newton-Schulz inverse of S ----
    hipMemsetAsync(cmax, 0, 4, stream);
    rowabsmax_kernel<<<dim3(512), blk, 0, stream>>>(Sf, 512, cmax);
    initx1_kernel<<<dim3(1024), blk, 0, stream>>>(Sf, 512, cmax, Xf);
    cvt_split_both_kernel<<<dim3(16, 16), blk, 0, stream>>>(
        Xf, 512, Xa_h, Xa_l, 512, Xt_h, Xt_l, 512, 512, 512);
    for (int it = 0; it < 7; ++it) {
        // Yt = (S @ X)^T
        MM(4, (float*)nullptr, 0, (us*)nullptr, (us*)nullptr, 0, Yt_h, Yt_l, 512,
           S_h, S_l, 512, Xt_h, Xt_l, 512, (const float*)nullptr, 0, 512, 512, 512, 1.f, 1.f);
        // X2 = 2X - X@Y -> fp32 + A-form + T-form
        MM(7, X2f, 512, X2a_h, X2a_l, 512, X2t_h, X2t_l, 512,
           Xa_h, Xa_l, 512, Yt_h, Yt_l, 512, Xf, 512, 512, 512, 512, -1.f, 2.f);
        { float* t = Xf; Xf = X2f; X2f = t; }
        { us* t = Xa_h; Xa_h = X2a_h; X2a_h = t; }
        { us* t = Xa_l; Xa_l = X2a_l; X2a_l = t; }
        { us* t = Xt_h; Xt_h = X2t_h; X2t_h = t; }
        { us* t = Xt_l; Xt_l = X2t_l; X2t_l = t; }
    }
    // Sinv^T == final Xt (exact T-form from epilogue)

    // ---- gain + covariance update ----
    // PHT = covp @ H^T -> split (amh)
    MM(2, (float*)nullptr, 0, amh_h, amh_l, 512, (us*)nullptr, (us*)nullptr, 0,
       cA_h, cA_l, 1024, H_h, H_l, 1024, (const float*)nullptr, 0, 1024, 512, 1024, 1.f, 1.f);
    // Kg = PHT @ Sinv -> split
    MM(2, (float*)nullptr, 0, Kg_h, Kg_l, 512, (us*)nullptr, (us*)nullptr, 0,
       amh_h, amh_l, 512, Xt_h, Xt_l, 512, (const float*)nullptr, 0, 1024, 512, 512, 1.f, 1.f);
    // KH = Kg @ H -> split
    MM(2, (float*)nullptr, 0, KH_h, KH_l, 1024, (us*)nullptr, (us*)nullptr, 0,
       Kg_h, Kg_l, 512, HT_h, HT_l, 512, (const float*)nullptr, 0, 1024, 1024, 512, 1.f, 1.f);
    // cov_n = covp - KH @ covp -> fp32 out
    MM(1, out_cov, 1024, (us*)nullptr, (us*)nullptr, 0, (us*)nullptr, (us*)nullptr, 0,
       KH_h, KH_l, 1024, cT_h, cT_l, 1024, covp, 1024, 1024, 1024, 1024, -1.f, 1.f);

    // ---- state chain ----
    for (int b0 = 0; b0 < Bb; b0 += NC) {
        cvtT(state + b0, 8192, ar_h, ar_l, 1280, 1024, NC);
        cvtT(control + b0, 8192, ar_h + 1024, ar_l + 1024, 1280, 256, NC);
        // state_p = [F|Bc] @ [state;control] -> fp32 (out_state)
        MM(1, out_state + b0, 8192, (us*)nullptr, (us*)nullptr, 0, (us*)nullptr, (us*)nullptr, 0,
           FBc_h, FBc_l, 1280, ar_h, ar_l, 1280, (const float*)nullptr, 0, 1024, NC, 1280, 1.f, 1.f);
        cvtT(out_state + b0, 8192, ar_h, ar_l, 1024, 1024, NC);    // state_p^T (overwrite ar)
        // innov^T = (meas - H@state_p)^T -> transposed split
        MM(4, (float*)nullptr, 0, (us*)nullptr, (us*)nullptr, 0, ivT_h, ivT_l, 512,
           H_h, H_l, 1024, ar_h, ar_l, 1024, meas + b0, 8192, 512, NC, 1024, -1.f, 1.f);
        // state_n = state_p + Kg @ innov -> fp32 (in place)
        MM(1, out_state + b0, 8192, (us*)nullptr, (us*)nullptr, 0, (us*)nullptr, (us*)nullptr, 0,
           Kg_h, Kg_l, 512, ivT_h, ivT_l, 512, out_state + b0, 8192, 1024, NC, 512, 1.f, 1.f);
    }
#undef MM
}